// Round 1
// baseline (9971.194 us; speedup 1.0000x reference)
//
#include <hip/hip_runtime.h>

#define L_SEQ 1024
#define B_SZ  16
#define D_SZ  512
#define V_SZ  10000

typedef __attribute__((ext_vector_type(8))) short bf16x8;
typedef __attribute__((ext_vector_type(4))) float f32x4;

__device__ __forceinline__ float bf2f(unsigned int u) {
  unsigned int x = (u & 0xffffu) << 16;
  return __builtin_bit_cast(float, x);
}
__device__ __forceinline__ unsigned short f2bf(float f) {
  unsigned int x = __builtin_bit_cast(unsigned int, f);
  x += 0x7fffu + ((x >> 16) & 1u);
  return (unsigned short)(x >> 16);
}
__device__ __forceinline__ unsigned int pk2(float lo, float hi) {
  return (unsigned int)f2bf(lo) | ((unsigned int)f2bf(hi) << 16);
}
__device__ __forceinline__ float sigm(float x) { return 1.f / (1.f + __expf(-x)); }
__device__ __forceinline__ float tanhfast(float x) {
  x = fminf(fmaxf(x, -15.f), 15.f);
  float e = __expf(2.f * x);
  return (e - 1.f) / (e + 1.f);
}

#define KPAD 40  // LDS row stride (bf16 elems): 80B, 16B-aligned, 2-way-bank-free

// ---------------- K1: gi = gather(emb, tokens) @ W_ih^T + b_ih ----------------
// rows r = t*16+b (M=16384), cols j (N=1536), K=512. Output transposed: giT[t][j][b] bf16.
__global__ __launch_bounds__(256) void k_gi(
    const int* __restrict__ tokens, const float* __restrict__ emb,
    const float* __restrict__ Wih, const float* __restrict__ bih,
    unsigned short* __restrict__ giT)
{
  __shared__ unsigned short As[64 * KPAD];
  __shared__ unsigned short Bs[64 * KPAD];
  const int tid = threadIdx.x, lane = tid & 63, wv = tid >> 6;
  const int m0 = blockIdx.y * 64, n0 = blockIdx.x * 64;
  const int sr = tid >> 2, skc = (tid & 3) * 8;
  const int grow = m0 + sr;
  const int tok = tokens[((grow & 15) << 10) + (grow >> 4)];
  const float* asrc = emb + (size_t)tok * 512 + skc;
  const float* bsrc = Wih + (size_t)(n0 + sr) * 512 + skc;

  f32x4 acc[4];
  #pragma unroll
  for (int i = 0; i < 4; ++i) acc[i] = 0.f;

  for (int ks = 0; ks < 16; ++ks) {
    __syncthreads();
    float4 a0 = *(const float4*)(asrc + ks * 32);
    float4 a1 = *(const float4*)(asrc + ks * 32 + 4);
    float4 q0 = *(const float4*)(bsrc + ks * 32);
    float4 q1 = *(const float4*)(bsrc + ks * 32 + 4);
    uint4 ua = { pk2(a0.x, a0.y), pk2(a0.z, a0.w), pk2(a1.x, a1.y), pk2(a1.z, a1.w) };
    uint4 ub = { pk2(q0.x, q0.y), pk2(q0.z, q0.w), pk2(q1.x, q1.y), pk2(q1.z, q1.w) };
    *(uint4*)&As[sr * KPAD + skc] = ua;
    *(uint4*)&Bs[sr * KPAD + skc] = ub;
    __syncthreads();
    bf16x8 af = *(const bf16x8*)&As[(wv * 16 + (lane & 15)) * KPAD + (lane >> 4) * 8];
    #pragma unroll
    for (int ns = 0; ns < 4; ++ns) {
      bf16x8 bfv = *(const bf16x8*)&Bs[(ns * 16 + (lane & 15)) * KPAD + (lane >> 4) * 8];
      acc[ns] = __builtin_amdgcn_mfma_f32_16x16x32_bf16(af, bfv, acc[ns], 0, 0, 0);
    }
  }
  const int mrow = m0 + wv * 16 + 4 * (lane >> 4);
  const int ncol = n0 + (lane & 15);
  #pragma unroll
  for (int ns = 0; ns < 4; ++ns) {
    int col = ncol + ns * 16;
    float bv = bih[col];
    #pragma unroll
    for (int rr = 0; rr < 4; ++rr) {
      int row = mrow + rr;
      giT[((size_t)(row >> 4) * 1536 + col) * 16 + (row & 15)] = f2bf(acc[ns][rr] + bv);
    }
  }
}

// ---------------- K2: persistent fused scan ----------------
// blocks 0..63  : producers. WG w owns h-dims [w*8,w*8+8) and gxp cols [w*4,w*4+4).
//   Weights (24 gh rows + 12 gxp rows, padded to 48) resident in LDS (row stride 520 bf16).
//   Per step: read h(t-1) bf16 (16KB via L2) -> 48 MFMAs -> pointwise GRU -> write h(t) slice
//   + write g/x/xp(t-1) streams. One release/acquire slot sync per step.
// blocks 64..191: consumers. WG (b, sl) owns M[b][:, sl*32..+32) in LDS f32 (32KB).
//   Per step: retr slice (read-before-update), M += g x^T slice, x_hat = 0.5*xp + 0.5*retr.
__global__ __launch_bounds__(64) void k_scan(
    const unsigned short* __restrict__ giT,
    const float* __restrict__ Whh, const float* __restrict__ bhh,
    const float* __restrict__ Wg, const float* __restrict__ bg,
    const float* __restrict__ Wx, const float* __restrict__ bx,
    const float* __restrict__ Wp, const float* __restrict__ bp,
    unsigned short* __restrict__ gS, unsigned short* __restrict__ xS,
    unsigned short* __restrict__ xpS, unsigned short* __restrict__ xhat,
    unsigned short* __restrict__ hbuf, int* __restrict__ bar)
{
  __shared__ char smem[53248];
  const int lane = threadIdx.x;
  const int wid = blockIdx.x;

  if (wid < 64) {
    unsigned short* wlds = (unsigned short*)smem;                   // 48 x 520 bf16
    float* scr = (float*)(smem + 49920);                            // [3][16][16] f32
    unsigned short* hpack = (unsigned short*)(smem + 49920 + 3072); // [16][8] bf16
    const int w = wid;

    for (int row = 0; row < 48; ++row) {
      const float* src = nullptr;
      if (row < 24)                   src = Whh + (size_t)((row >> 3) * 512 + w * 8 + (row & 7)) * 512;
      else if (row >= 32 && row < 36) src = Wg + (size_t)(w * 4 + row - 32) * 512;
      else if (row >= 36 && row < 40) src = Wx + (size_t)(w * 4 + row - 36) * 512;
      else if (row >= 40 && row < 44) src = Wp + (size_t)(w * 4 + row - 40) * 512;
      uint4 u = {0u, 0u, 0u, 0u};
      if (src) {
        float4 p0 = *(const float4*)(src + lane * 8);
        float4 p1 = *(const float4*)(src + lane * 8 + 4);
        u.x = pk2(p0.x, p0.y); u.y = pk2(p0.z, p0.w);
        u.z = pk2(p1.x, p1.y); u.w = pk2(p1.z, p1.w);
      }
      *(uint4*)&wlds[row * 520 + lane * 8] = u;
    }
    __syncthreads();

    const int b_ = lane & 15;
    const int dd1 = lane >> 4, dd2 = (lane >> 4) + 4;
    const float bhr1 = bhh[w * 8 + dd1], bhz1 = bhh[512 + w * 8 + dd1], bhn1 = bhh[1024 + w * 8 + dd1];
    const float bhr2 = bhh[w * 8 + dd2], bhz2 = bhh[512 + w * 8 + dd2], bhn2 = bhh[1024 + w * 8 + dd2];
    const int cg = lane >> 4;
    const float bgv = bg[w * 4 + cg], bxv = bx[w * 4 + cg], bpv = bp[w * 4 + cg];
    float hprev1 = 0.f, hprev2 = 0.f;

    #pragma unroll 1
    for (int t = 0; t <= L_SEQ; ++t) {
      float gir1 = 0, giz1 = 0, gin1 = 0, gir2 = 0, giz2 = 0, gin2 = 0;
      if (t < L_SEQ) {  // gi prefetch (independent of the sync)
        const unsigned short* gib = giT + (size_t)t * 1536 * 16 + b_;
        gir1 = bf2f(gib[(size_t)(w * 8 + dd1) * 16]);
        giz1 = bf2f(gib[(size_t)(512 + w * 8 + dd1) * 16]);
        gin1 = bf2f(gib[(size_t)(1024 + w * 8 + dd1) * 16]);
        gir2 = bf2f(gib[(size_t)(w * 8 + dd2) * 16]);
        giz2 = bf2f(gib[(size_t)(512 + w * 8 + dd2) * 16]);
        gin2 = bf2f(gib[(size_t)(1024 + w * 8 + dd2) * 16]);
      }
      if (t > 0) {
        int spins = 0;
        for (;;) {
          int v = __hip_atomic_load(&bar[lane], __ATOMIC_ACQUIRE, __HIP_MEMORY_SCOPE_AGENT);
          if (__all(v >= t)) break;
          __builtin_amdgcn_s_sleep(1);
          if (++spins > 50000000) break;
        }
      }
      bf16x8 afr[16];
      if (t > 0) {
        const unsigned short* hsrc = hbuf + (size_t)((t - 1) & 1) * 8192 + (size_t)b_ * 512 + (lane >> 4) * 8;
        #pragma unroll
        for (int kk = 0; kk < 16; ++kk) afr[kk] = *(const bf16x8*)(hsrc + kk * 32);
      } else {
        bf16x8 z = {0, 0, 0, 0, 0, 0, 0, 0};
        #pragma unroll
        for (int kk = 0; kk < 16; ++kk) afr[kk] = z;
      }
      f32x4 a0 = 0.f, a1 = 0.f, a2 = 0.f;
      const unsigned short* bbase = wlds + (size_t)b_ * 520 + (lane >> 4) * 8;
      #pragma unroll
      for (int kk = 0; kk < 16; ++kk) {
        bf16x8 b0 = *(const bf16x8*)(bbase + kk * 32);
        bf16x8 b1 = *(const bf16x8*)(bbase + 16 * 520 + kk * 32);
        bf16x8 b2 = *(const bf16x8*)(bbase + 32 * 520 + kk * 32);
        a0 = __builtin_amdgcn_mfma_f32_16x16x32_bf16(afr[kk], b0, a0, 0, 0, 0);
        a1 = __builtin_amdgcn_mfma_f32_16x16x32_bf16(afr[kk], b1, a1, 0, 0, 0);
        a2 = __builtin_amdgcn_mfma_f32_16x16x32_bf16(afr[kk], b2, a2, 0, 0, 0);
      }
      {
        int m = 4 * (lane >> 4);
        #pragma unroll
        for (int rr = 0; rr < 4; ++rr) {
          scr[(m + rr) * 16 + b_] = a0[rr];
          scr[256 + (m + rr) * 16 + b_] = a1[rr];
          scr[512 + (m + rr) * 16 + b_] = a2[rr];
        }
      }
      __syncthreads();
      if (t < L_SEQ) {
        float r1 = sigm(scr[b_ * 16 + dd1] + gir1 + bhr1);
        float z1 = sigm(scr[b_ * 16 + 8 + dd1] + giz1 + bhz1);
        float n1 = tanhfast(gin1 + r1 * (scr[256 + b_ * 16 + dd1] + bhn1));
        float h1 = (1.f - z1) * n1 + z1 * hprev1; hprev1 = h1;
        float r2 = sigm(scr[b_ * 16 + dd2] + gir2 + bhr2);
        float z2 = sigm(scr[b_ * 16 + 8 + dd2] + giz2 + bhz2);
        float n2 = tanhfast(gin2 + r2 * (scr[256 + b_ * 16 + dd2] + bhn2));
        float h2 = (1.f - z2) * n2 + z2 * hprev2; hprev2 = h2;
        hpack[b_ * 8 + dd1] = f2bf(h1);
        hpack[b_ * 8 + dd2] = f2bf(h2);
      }
      if (t > 0) {  // emit g/x/xp for step t-1
        float gv = scr[512 + b_ * 16 + cg] + bgv;
        float xv = scr[512 + b_ * 16 + 4 + cg] + bxv;
        float xpv = scr[512 + b_ * 16 + 8 + cg] + bpv;
        size_t sbase = ((size_t)(t - 1) * 16 + b_) * 256 + w * 4 + cg;
        gS[sbase] = f2bf(gv);
        xS[sbase] = f2bf(xv);
        xpS[sbase] = f2bf(xpv);
      }
      __syncthreads();
      if (t < L_SEQ && lane < 16) {
        *(uint4*)(hbuf + (size_t)(t & 1) * 8192 + (size_t)lane * 512 + w * 8) =
            *(const uint4*)&hpack[lane * 8];
      }
      if (lane == 0)
        __hip_atomic_store(&bar[w], t + 1, __ATOMIC_RELEASE, __HIP_MEMORY_SCOPE_AGENT);
    }
  } else {
    float* Msh = (float*)smem;  // [256][32] f32 (batch-local M column slice)
    const int id = wid - 64;
    const int b = id >> 3, sl = id & 7;
    const int colg = lane & 7, dgs = lane >> 3;
    for (int i = lane * 4; i < 8192; i += 256) *(float4*)&Msh[i] = float4{0.f, 0.f, 0.f, 0.f};
    __syncthreads();
    #pragma unroll 1
    for (int t = 0; t < L_SEQ; ++t) {
      {
        int spins = 0;
        for (;;) {
          int v = __hip_atomic_load(&bar[lane], __ATOMIC_ACQUIRE, __HIP_MEMORY_SCOPE_AGENT);
          if (__all(v >= t + 2)) break;
          __builtin_amdgcn_s_sleep(1);
          if (++spins > 50000000) break;
        }
      }
      size_t rb = ((size_t)t * 16 + b) * 256;
      uint2 xraw = *(const uint2*)(xS + rb + sl * 32 + colg * 4);
      uint2 praw = *(const uint2*)(xpS + rb + sl * 32 + colg * 4);
      float xv0 = bf2f(xraw.x), xv1 = bf2f(xraw.x >> 16), xv2 = bf2f(xraw.y), xv3 = bf2f(xraw.y >> 16);
      float r0 = 0, r1 = 0, r2 = 0, r3 = 0;
      const unsigned short* gp = gS + rb + dgs * 32;
      #pragma unroll
      for (int ic = 0; ic < 8; ++ic) {
        uint2 graw = *(const uint2*)(gp + ic * 4);
        float gj[4] = { bf2f(graw.x), bf2f(graw.x >> 16), bf2f(graw.y), bf2f(graw.y >> 16) };
        int dg = dgs * 32 + ic * 4;
        #pragma unroll
        for (int j = 0; j < 4; ++j) {
          float4* mp = (float4*)&Msh[(dg + j) * 32 + colg * 4];
          float4 m = *mp;
          r0 += gj[j] * m.x; r1 += gj[j] * m.y; r2 += gj[j] * m.z; r3 += gj[j] * m.w;
          m.x += gj[j] * xv0; m.y += gj[j] * xv1; m.z += gj[j] * xv2; m.w += gj[j] * xv3;
          *mp = m;
        }
      }
      #pragma unroll
      for (int off = 8; off < 64; off <<= 1) {
        r0 += __shfl_xor(r0, off); r1 += __shfl_xor(r1, off);
        r2 += __shfl_xor(r2, off); r3 += __shfl_xor(r3, off);
      }
      if (dgs == 0) {
        float y0 = 0.5f * bf2f(praw.x) + 0.5f * r0;
        float y1 = 0.5f * bf2f(praw.x >> 16) + 0.5f * r1;
        float y2 = 0.5f * bf2f(praw.y) + 0.5f * r2;
        float y3 = 0.5f * bf2f(praw.y >> 16) + 0.5f * r3;
        uint2 ou = { pk2(y0, y1), pk2(y2, y3) };
        *(uint2*)(xhat + rb + sl * 32 + colg * 4) = ou;
      }
    }
  }
}

// ---------------- K3: LayerNorm over x_hat rows (256 wide) ----------------
__global__ __launch_bounds__(256) void k_ln(
    const unsigned short* __restrict__ xh, const float* __restrict__ g,
    const float* __restrict__ bta, unsigned short* __restrict__ o)
{
  int row = blockIdx.x * 4 + (threadIdx.x >> 6);
  int lane = threadIdx.x & 63;
  size_t base = (size_t)row * 256 + lane * 4;
  uint2 raw = *(const uint2*)(xh + base);
  float v0 = bf2f(raw.x), v1 = bf2f(raw.x >> 16), v2 = bf2f(raw.y), v3 = bf2f(raw.y >> 16);
  float s1 = v0 + v1 + v2 + v3;
  float s2 = v0 * v0 + v1 * v1 + v2 * v2 + v3 * v3;
  #pragma unroll
  for (int off = 1; off < 64; off <<= 1) { s1 += __shfl_xor(s1, off); s2 += __shfl_xor(s2, off); }
  float mu = s1 * (1.f / 256.f);
  float var = s2 * (1.f / 256.f) - mu * mu;
  float rs = rsqrtf(var + 1e-5f);
  int c = lane * 4;
  float y0 = (v0 - mu) * rs * g[c] + bta[c];
  float y1 = (v1 - mu) * rs * g[c + 1] + bta[c + 1];
  float y2 = (v2 - mu) * rs * g[c + 2] + bta[c + 2];
  float y3 = (v3 - mu) * rs * g[c + 3] + bta[c + 3];
  uint2 ou = { pk2(y0, y1), pk2(y2, y3) };
  *(uint2*)(o + base) = ou;
}

// ---------------- K4: logits = LN(x_hat) @ Wo^T + bo -> out (B,L,V) f32 ----------------
__global__ __launch_bounds__(256) void k_logits(
    const unsigned short* __restrict__ ln, const float* __restrict__ Wo,
    const float* __restrict__ bo, float* __restrict__ out)
{
  __shared__ unsigned short As[64 * KPAD];
  __shared__ unsigned short Bs[64 * KPAD];
  const int tid = threadIdx.x, lane = tid & 63, wv = tid >> 6;
  const int m0 = blockIdx.y * 64, n0 = blockIdx.x * 64;
  const int sr = tid >> 2, skc = (tid & 3) * 8;
  const unsigned short* asrc = ln + (size_t)(m0 + sr) * 256 + skc;
  const int brow = n0 + sr;
  const bool bok = brow < V_SZ;
  const float* bsrc = Wo + (size_t)(bok ? brow : 0) * 256 + skc;

  f32x4 acc[4];
  #pragma unroll
  for (int i = 0; i < 4; ++i) acc[i] = 0.f;

  for (int ks = 0; ks < 8; ++ks) {
    __syncthreads();
    *(uint4*)&As[sr * KPAD + skc] = *(const uint4*)(asrc + ks * 32);
    uint4 ub = {0u, 0u, 0u, 0u};
    if (bok) {
      float4 q0 = *(const float4*)(bsrc + ks * 32);
      float4 q1 = *(const float4*)(bsrc + ks * 32 + 4);
      ub.x = pk2(q0.x, q0.y); ub.y = pk2(q0.z, q0.w);
      ub.z = pk2(q1.x, q1.y); ub.w = pk2(q1.z, q1.w);
    }
    *(uint4*)&Bs[sr * KPAD + skc] = ub;
    __syncthreads();
    bf16x8 af = *(const bf16x8*)&As[(wv * 16 + (lane & 15)) * KPAD + (lane >> 4) * 8];
    #pragma unroll
    for (int ns = 0; ns < 4; ++ns) {
      bf16x8 bfv = *(const bf16x8*)&Bs[(ns * 16 + (lane & 15)) * KPAD + (lane >> 4) * 8];
      acc[ns] = __builtin_amdgcn_mfma_f32_16x16x32_bf16(af, bfv, acc[ns], 0, 0, 0);
    }
  }
  const int mrow = m0 + wv * 16 + 4 * (lane >> 4);
  const int ncol = n0 + (lane & 15);
  #pragma unroll
  for (int ns = 0; ns < 4; ++ns) {
    int col = ncol + ns * 16;
    if (col < V_SZ) {
      float bv = bo[col];
      #pragma unroll
      for (int rr = 0; rr < 4; ++rr) {
        int row = mrow + rr;
        out[(size_t)(row & 15) * ((size_t)L_SEQ * V_SZ) + (size_t)(row >> 4) * V_SZ + col] =
            acc[ns][rr] + bv;
      }
    }
  }
}

extern "C" void kernel_launch(void* const* d_in, const int* in_sizes, int n_in,
                              void* d_out, int out_size, void* d_ws, size_t ws_size,
                              hipStream_t stream)
{
  const int*   tokens = (const int*)d_in[0];
  const float* emb    = (const float*)d_in[1];
  const float* Wih    = (const float*)d_in[2];
  const float* Whh    = (const float*)d_in[3];
  const float* bih    = (const float*)d_in[4];
  const float* bhh    = (const float*)d_in[5];
  const float* Wg     = (const float*)d_in[6];
  const float* bg     = (const float*)d_in[7];
  const float* Wx     = (const float*)d_in[8];
  const float* bx     = (const float*)d_in[9];
  const float* Wp     = (const float*)d_in[10];
  const float* bp     = (const float*)d_in[11];
  const float* lng    = (const float*)d_in[12];
  const float* lnb    = (const float*)d_in[13];
  const float* Wo     = (const float*)d_in[14];
  const float* bo     = (const float*)d_in[15];
  float* out = (float*)d_out;

  char* ws = (char*)d_ws;
  size_t off = 0;
  auto take = [&](size_t bytes) -> char* {
    char* p = ws + off;
    off += (bytes + 255) & ~(size_t)255;
    return p;
  };
  unsigned short* giT  = (unsigned short*)take((size_t)1024 * 1536 * 16 * 2); // 50.3 MB
  unsigned short* gS   = (unsigned short*)take((size_t)1024 * 16 * 256 * 2);  // 8.4 MB
  unsigned short* xS   = (unsigned short*)take((size_t)1024 * 16 * 256 * 2);
  unsigned short* xpS  = (unsigned short*)take((size_t)1024 * 16 * 256 * 2);
  unsigned short* xhat = (unsigned short*)take((size_t)1024 * 16 * 256 * 2);
  unsigned short* lnO  = (unsigned short*)take((size_t)1024 * 16 * 256 * 2);
  unsigned short* hbuf = (unsigned short*)take((size_t)2 * 16 * 512 * 2);
  int* bar             = (int*)take(256);
  if (off > ws_size) return;  // workspace too small -> visible absmax failure

  (void)hipMemsetAsync(bar, 0, 256, stream);  // replay-safe sync-slot reset

  k_gi<<<dim3(24, 256), 256, 0, stream>>>(tokens, emb, Wih, bih, giT);
  k_scan<<<192, 64, 0, stream>>>(giT, Whh, bhh, Wg, bg, Wx, bx, Wp, bp,
                                 gS, xS, xpS, xhat, hbuf, bar);
  k_ln<<<4096, 256, 0, stream>>>(xhat, lng, lnb, lnO);
  k_logits<<<dim3(157, 256), 256, 0, stream>>>(lnO, Wo, bo, out);
}

// Round 2
// 6366.638 us; speedup vs baseline: 1.5662x; 1.5662x over previous
//
#include <hip/hip_runtime.h>

#define L_SEQ 1024
#define B_SZ  16
#define D_SZ  512
#define V_SZ  10000

typedef __attribute__((ext_vector_type(8))) short bf16x8;
typedef __attribute__((ext_vector_type(4))) float f32x4;
typedef __attribute__((ext_vector_type(4))) unsigned int u32x4;
typedef __attribute__((ext_vector_type(2))) unsigned int u32x2;

__device__ __forceinline__ float bf2f(unsigned int u) {
  unsigned int x = (u & 0xffffu) << 16;
  return __builtin_bit_cast(float, x);
}
__device__ __forceinline__ unsigned short f2bf(float f) {
  unsigned int x = __builtin_bit_cast(unsigned int, f);
  x += 0x7fffu + ((x >> 16) & 1u);
  return (unsigned short)(x >> 16);
}
__device__ __forceinline__ unsigned int pk2(float lo, float hi) {
  return (unsigned int)f2bf(lo) | ((unsigned int)f2bf(hi) << 16);
}
__device__ __forceinline__ float sigm(float x) { return 1.f / (1.f + __expf(-x)); }
__device__ __forceinline__ float tanhfast(float x) {
  x = fminf(fmaxf(x, -15.f), 15.f);
  float e = __expf(2.f * x);
  return (e - 1.f) / (e + 1.f);
}

// ---- LLC-coherent (cross-XCD) access helpers: sc0 sc1 = bypass L1+L2,
// perform at Infinity Cache. NO buffer_inv / buffer_wbl2 (the R1 killer). ----
__device__ __forceinline__ void llc_store_u32(void* p, unsigned int v) {
  asm volatile("global_store_dword %0, %1, off sc0 sc1" :: "v"(p), "v"(v) : "memory");
}
__device__ __forceinline__ void llc_store_u16(void* p, unsigned int v) {
  asm volatile("global_store_short %0, %1, off sc0 sc1" :: "v"(p), "v"(v) : "memory");
}
__device__ __forceinline__ void vm_drain() {
  asm volatile("s_waitcnt vmcnt(0)" ::: "memory");
}

#define KPAD 40  // LDS row stride (bf16 elems): 80B, 16B-aligned

// ---------------- K1: gi = gather(emb, tokens) @ W_ih^T + b_ih ----------------
__global__ __launch_bounds__(256) void k_gi(
    const int* __restrict__ tokens, const float* __restrict__ emb,
    const float* __restrict__ Wih, const float* __restrict__ bih,
    unsigned short* __restrict__ giT)
{
  __shared__ unsigned short As[64 * KPAD];
  __shared__ unsigned short Bs[64 * KPAD];
  const int tid = threadIdx.x, lane = tid & 63, wv = tid >> 6;
  const int m0 = blockIdx.y * 64, n0 = blockIdx.x * 64;
  const int sr = tid >> 2, skc = (tid & 3) * 8;
  const int grow = m0 + sr;
  const int tok = tokens[((grow & 15) << 10) + (grow >> 4)];
  const float* asrc = emb + (size_t)tok * 512 + skc;
  const float* bsrc = Wih + (size_t)(n0 + sr) * 512 + skc;

  f32x4 acc[4];
  #pragma unroll
  for (int i = 0; i < 4; ++i) acc[i] = 0.f;

  for (int ks = 0; ks < 16; ++ks) {
    __syncthreads();
    float4 a0 = *(const float4*)(asrc + ks * 32);
    float4 a1 = *(const float4*)(asrc + ks * 32 + 4);
    float4 q0 = *(const float4*)(bsrc + ks * 32);
    float4 q1 = *(const float4*)(bsrc + ks * 32 + 4);
    uint4 ua = { pk2(a0.x, a0.y), pk2(a0.z, a0.w), pk2(a1.x, a1.y), pk2(a1.z, a1.w) };
    uint4 ub = { pk2(q0.x, q0.y), pk2(q0.z, q0.w), pk2(q1.x, q1.y), pk2(q1.z, q1.w) };
    *(uint4*)&As[sr * KPAD + skc] = ua;
    *(uint4*)&Bs[sr * KPAD + skc] = ub;
    __syncthreads();
    bf16x8 af = *(const bf16x8*)&As[(wv * 16 + (lane & 15)) * KPAD + (lane >> 4) * 8];
    #pragma unroll
    for (int ns = 0; ns < 4; ++ns) {
      bf16x8 bfv = *(const bf16x8*)&Bs[(ns * 16 + (lane & 15)) * KPAD + (lane >> 4) * 8];
      acc[ns] = __builtin_amdgcn_mfma_f32_16x16x32_bf16(af, bfv, acc[ns], 0, 0, 0);
    }
  }
  const int mrow = m0 + wv * 16 + 4 * (lane >> 4);
  const int ncol = n0 + (lane & 15);
  #pragma unroll
  for (int ns = 0; ns < 4; ++ns) {
    int col = ncol + ns * 16;
    float bv = bih[col];
    #pragma unroll
    for (int rr = 0; rr < 4; ++rr) {
      int row = mrow + rr;
      giT[((size_t)(row >> 4) * 1536 + col) * 16 + (row & 15)] = f2bf(acc[ns][rr] + bv);
    }
  }
}

// ---------------- K2: persistent fused scan ----------------
// Producers (WG 0..63): weights in LDS, per step: MFMA gh+gxp, pointwise GRU,
//   write h + streams via sc0sc1 stores, vmcnt(0), relaxed flag. Poll = relaxed.
// Consumers (WG 64..191): M slice in LDS f32, consume streams via sc0sc1 loads.
__global__ __launch_bounds__(64) void k_scan(
    const unsigned short* __restrict__ giT,
    const float* __restrict__ Whh, const float* __restrict__ bhh,
    const float* __restrict__ Wg, const float* __restrict__ bg,
    const float* __restrict__ Wx, const float* __restrict__ bx,
    const float* __restrict__ Wp, const float* __restrict__ bp,
    unsigned short* __restrict__ gS, unsigned short* __restrict__ xS,
    unsigned short* __restrict__ xpS, unsigned short* __restrict__ xhat,
    unsigned short* __restrict__ hbuf, int* __restrict__ bar)
{
  __shared__ char smem[53248];
  const int lane = threadIdx.x;
  const int wid = blockIdx.x;

  if (wid < 64) {
    unsigned short* wlds = (unsigned short*)smem;  // 48 x 520 bf16
    float* scr = (float*)(smem + 49920);           // [3][16][16] f32
    const int w = wid;

    for (int row = 0; row < 48; ++row) {
      const float* src = nullptr;
      if (row < 24)                   src = Whh + (size_t)((row >> 3) * 512 + w * 8 + (row & 7)) * 512;
      else if (row >= 32 && row < 36) src = Wg + (size_t)(w * 4 + row - 32) * 512;
      else if (row >= 36 && row < 40) src = Wx + (size_t)(w * 4 + row - 36) * 512;
      else if (row >= 40 && row < 44) src = Wp + (size_t)(w * 4 + row - 40) * 512;
      uint4 u = {0u, 0u, 0u, 0u};
      if (src) {
        float4 p0 = *(const float4*)(src + lane * 8);
        float4 p1 = *(const float4*)(src + lane * 8 + 4);
        u.x = pk2(p0.x, p0.y); u.y = pk2(p0.z, p0.w);
        u.z = pk2(p1.x, p1.y); u.w = pk2(p1.z, p1.w);
      }
      *(uint4*)&wlds[row * 520 + lane * 8] = u;
    }
    __syncthreads();

    const int b_ = lane & 15;
    const int hi = lane >> 4;
    const int dd1 = hi * 2, dd2 = hi * 2 + 1;      // adjacent dims -> packed h store
    const float bhr1 = bhh[w * 8 + dd1], bhz1 = bhh[512 + w * 8 + dd1], bhn1 = bhh[1024 + w * 8 + dd1];
    const float bhr2 = bhh[w * 8 + dd2], bhz2 = bhh[512 + w * 8 + dd2], bhn2 = bhh[1024 + w * 8 + dd2];
    const int cg = hi;
    const float bgv = bg[w * 4 + cg], bxv = bx[w * 4 + cg], bpv = bp[w * 4 + cg];
    float hprev1 = 0.f, hprev2 = 0.f;

    #pragma unroll 1
    for (int t = 0; t <= L_SEQ; ++t) {
      float gir1 = 0, giz1 = 0, gin1 = 0, gir2 = 0, giz2 = 0, gin2 = 0;
      if (t < L_SEQ) {  // gi prefetch (cached loads; hides under the spin)
        const unsigned short* gib = giT + (size_t)t * 1536 * 16 + b_;
        gir1 = bf2f(gib[(size_t)(w * 8 + dd1) * 16]);
        giz1 = bf2f(gib[(size_t)(512 + w * 8 + dd1) * 16]);
        gin1 = bf2f(gib[(size_t)(1024 + w * 8 + dd1) * 16]);
        gir2 = bf2f(gib[(size_t)(w * 8 + dd2) * 16]);
        giz2 = bf2f(gib[(size_t)(512 + w * 8 + dd2) * 16]);
        gin2 = bf2f(gib[(size_t)(1024 + w * 8 + dd2) * 16]);
      }
      if (t > 0) {
        int spins = 0;
        for (;;) {
          int v = __hip_atomic_load(&bar[lane], __ATOMIC_RELAXED, __HIP_MEMORY_SCOPE_AGENT);
          if (__all(v >= t)) break;
          __builtin_amdgcn_s_sleep(1);
          if (++spins > 3000000) break;
        }
      }
      bf16x8 afr[16];
      if (t > 0) {
        const unsigned short* hsrc = hbuf + (size_t)((t - 1) & 1) * 8192 + (size_t)b_ * 512 + hi * 8;
        u32x4 h0, h1v, h2v, h3, h4, h5, h6, h7, h8, h9, h10, h11, h12, h13, h14, h15;
        asm volatile(
          "global_load_dwordx4 %0, %16, off sc0 sc1\n\t"
          "global_load_dwordx4 %1, %16, off offset:64 sc0 sc1\n\t"
          "global_load_dwordx4 %2, %16, off offset:128 sc0 sc1\n\t"
          "global_load_dwordx4 %3, %16, off offset:192 sc0 sc1\n\t"
          "global_load_dwordx4 %4, %16, off offset:256 sc0 sc1\n\t"
          "global_load_dwordx4 %5, %16, off offset:320 sc0 sc1\n\t"
          "global_load_dwordx4 %6, %16, off offset:384 sc0 sc1\n\t"
          "global_load_dwordx4 %7, %16, off offset:448 sc0 sc1\n\t"
          "global_load_dwordx4 %8, %16, off offset:512 sc0 sc1\n\t"
          "global_load_dwordx4 %9, %16, off offset:576 sc0 sc1\n\t"
          "global_load_dwordx4 %10, %16, off offset:640 sc0 sc1\n\t"
          "global_load_dwordx4 %11, %16, off offset:704 sc0 sc1\n\t"
          "global_load_dwordx4 %12, %16, off offset:768 sc0 sc1\n\t"
          "global_load_dwordx4 %13, %16, off offset:832 sc0 sc1\n\t"
          "global_load_dwordx4 %14, %16, off offset:896 sc0 sc1\n\t"
          "global_load_dwordx4 %15, %16, off offset:960 sc0 sc1\n\t"
          "s_waitcnt vmcnt(0)"
          : "=&v"(h0), "=&v"(h1v), "=&v"(h2v), "=&v"(h3), "=&v"(h4), "=&v"(h5),
            "=&v"(h6), "=&v"(h7), "=&v"(h8), "=&v"(h9), "=&v"(h10), "=&v"(h11),
            "=&v"(h12), "=&v"(h13), "=&v"(h14), "=&v"(h15)
          : "v"(hsrc)
          : "memory");
        afr[0]  = __builtin_bit_cast(bf16x8, h0);  afr[1]  = __builtin_bit_cast(bf16x8, h1v);
        afr[2]  = __builtin_bit_cast(bf16x8, h2v); afr[3]  = __builtin_bit_cast(bf16x8, h3);
        afr[4]  = __builtin_bit_cast(bf16x8, h4);  afr[5]  = __builtin_bit_cast(bf16x8, h5);
        afr[6]  = __builtin_bit_cast(bf16x8, h6);  afr[7]  = __builtin_bit_cast(bf16x8, h7);
        afr[8]  = __builtin_bit_cast(bf16x8, h8);  afr[9]  = __builtin_bit_cast(bf16x8, h9);
        afr[10] = __builtin_bit_cast(bf16x8, h10); afr[11] = __builtin_bit_cast(bf16x8, h11);
        afr[12] = __builtin_bit_cast(bf16x8, h12); afr[13] = __builtin_bit_cast(bf16x8, h13);
        afr[14] = __builtin_bit_cast(bf16x8, h14); afr[15] = __builtin_bit_cast(bf16x8, h15);
      } else {
        bf16x8 z = {0, 0, 0, 0, 0, 0, 0, 0};
        #pragma unroll
        for (int kk = 0; kk < 16; ++kk) afr[kk] = z;
      }
      f32x4 a0 = 0.f, a1 = 0.f, a2 = 0.f;
      const unsigned short* bbase = wlds + (size_t)b_ * 520 + hi * 8;
      #pragma unroll
      for (int kk = 0; kk < 16; ++kk) {
        bf16x8 b0 = *(const bf16x8*)(bbase + kk * 32);
        bf16x8 b1 = *(const bf16x8*)(bbase + 16 * 520 + kk * 32);
        bf16x8 b2 = *(const bf16x8*)(bbase + 32 * 520 + kk * 32);
        a0 = __builtin_amdgcn_mfma_f32_16x16x32_bf16(afr[kk], b0, a0, 0, 0, 0);
        a1 = __builtin_amdgcn_mfma_f32_16x16x32_bf16(afr[kk], b1, a1, 0, 0, 0);
        a2 = __builtin_amdgcn_mfma_f32_16x16x32_bf16(afr[kk], b2, a2, 0, 0, 0);
      }
      {
        int m = 4 * hi;
        #pragma unroll
        for (int rr = 0; rr < 4; ++rr) {
          scr[(m + rr) * 16 + b_] = a0[rr];
          scr[256 + (m + rr) * 16 + b_] = a1[rr];
          scr[512 + (m + rr) * 16 + b_] = a2[rr];
        }
      }
      __syncthreads();
      if (t < L_SEQ) {
        float r1 = sigm(scr[b_ * 16 + dd1] + gir1 + bhr1);
        float z1 = sigm(scr[b_ * 16 + 8 + dd1] + giz1 + bhz1);
        float n1 = tanhfast(gin1 + r1 * (scr[256 + b_ * 16 + dd1] + bhn1));
        float h1 = (1.f - z1) * n1 + z1 * hprev1; hprev1 = h1;
        float r2 = sigm(scr[b_ * 16 + dd2] + gir2 + bhr2);
        float z2 = sigm(scr[b_ * 16 + 8 + dd2] + giz2 + bhz2);
        float n2 = tanhfast(gin2 + r2 * (scr[256 + b_ * 16 + dd2] + bhn2));
        float h2 = (1.f - z2) * n2 + z2 * hprev2; hprev2 = h2;
        // direct packed h store (2 adjacent dims per lane)
        unsigned short* hdst = hbuf + (size_t)(t & 1) * 8192 + (size_t)b_ * 512 + w * 8 + dd1;
        llc_store_u32(hdst, pk2(h1, h2));
      }
      if (t > 0) {  // emit g/x/xp for step t-1
        float gv = scr[512 + b_ * 16 + cg] + bgv;
        float xv = scr[512 + b_ * 16 + 4 + cg] + bxv;
        float xpv = scr[512 + b_ * 16 + 8 + cg] + bpv;
        size_t sbase = ((size_t)(t - 1) * 16 + b_) * 256 + w * 4 + cg;
        llc_store_u16(gS + sbase, (unsigned int)f2bf(gv));
        llc_store_u16(xS + sbase, (unsigned int)f2bf(xv));
        llc_store_u16(xpS + sbase, (unsigned int)f2bf(xpv));
      }
      vm_drain();  // all wave stores at coherence point
      if (lane == 0)
        __hip_atomic_store(&bar[w], t + 1, __ATOMIC_RELAXED, __HIP_MEMORY_SCOPE_AGENT);
      __syncthreads();  // protect scr WAR for next iteration
    }
  } else {
    float* Msh = (float*)smem;  // [256][32] f32
    const int id = wid - 64;
    const int b = id >> 3, sl = id & 7;
    const int colg = lane & 7, dgs = lane >> 3;
    for (int i = lane * 4; i < 8192; i += 256) *(float4*)&Msh[i] = float4{0.f, 0.f, 0.f, 0.f};
    __syncthreads();
    #pragma unroll 1
    for (int t = 0; t < L_SEQ; ++t) {
      {
        int spins = 0;
        for (;;) {
          int v = __hip_atomic_load(&bar[lane], __ATOMIC_RELAXED, __HIP_MEMORY_SCOPE_AGENT);
          if (__all(v >= t + 2)) break;
          __builtin_amdgcn_s_sleep(1);
          if (++spins > 3000000) break;
        }
      }
      size_t rb = ((size_t)t * 16 + b) * 256;
      const unsigned short* px = xS + rb + sl * 32 + colg * 4;
      const unsigned short* pp = xpS + rb + sl * 32 + colg * 4;
      const unsigned short* pg = gS + rb + dgs * 32;
      u32x2 xr, pr;
      u32x4 gq0, gq1, gq2, gq3;
      asm volatile(
        "global_load_dwordx2 %0, %6, off sc0 sc1\n\t"
        "global_load_dwordx2 %1, %7, off sc0 sc1\n\t"
        "global_load_dwordx4 %2, %8, off sc0 sc1\n\t"
        "global_load_dwordx4 %3, %8, off offset:16 sc0 sc1\n\t"
        "global_load_dwordx4 %4, %8, off offset:32 sc0 sc1\n\t"
        "global_load_dwordx4 %5, %8, off offset:48 sc0 sc1\n\t"
        "s_waitcnt vmcnt(0)"
        : "=&v"(xr), "=&v"(pr), "=&v"(gq0), "=&v"(gq1), "=&v"(gq2), "=&v"(gq3)
        : "v"(px), "v"(pp), "v"(pg)
        : "memory");
      float xv0 = bf2f(xr.x), xv1 = bf2f(xr.x >> 16), xv2 = bf2f(xr.y), xv3 = bf2f(xr.y >> 16);
      float r0 = 0, r1 = 0, r2 = 0, r3 = 0;
      unsigned int gw[8] = { gq0.x, gq0.y, gq0.z, gq0.w, gq1.x, gq1.y, gq1.z, gq1.w };
      unsigned int gw2[8] = { gq2.x, gq2.y, gq2.z, gq2.w, gq3.x, gq3.y, gq3.z, gq3.w };
      #pragma unroll
      for (int ic = 0; ic < 8; ++ic) {
        unsigned int lo = (ic < 4) ? gw[ic * 2] : gw2[(ic - 4) * 2];
        unsigned int hi2 = (ic < 4) ? gw[ic * 2 + 1] : gw2[(ic - 4) * 2 + 1];
        float gj[4] = { bf2f(lo), bf2f(lo >> 16), bf2f(hi2), bf2f(hi2 >> 16) };
        int dg = dgs * 32 + ic * 4;
        #pragma unroll
        for (int j = 0; j < 4; ++j) {
          float4* mp = (float4*)&Msh[(dg + j) * 32 + colg * 4];
          float4 m = *mp;
          r0 += gj[j] * m.x; r1 += gj[j] * m.y; r2 += gj[j] * m.z; r3 += gj[j] * m.w;
          m.x += gj[j] * xv0; m.y += gj[j] * xv1; m.z += gj[j] * xv2; m.w += gj[j] * xv3;
          *mp = m;
        }
      }
      #pragma unroll
      for (int off = 8; off < 64; off <<= 1) {
        r0 += __shfl_xor(r0, off); r1 += __shfl_xor(r1, off);
        r2 += __shfl_xor(r2, off); r3 += __shfl_xor(r3, off);
      }
      if (dgs == 0) {
        float y0 = 0.5f * bf2f(pr.x) + 0.5f * r0;
        float y1 = 0.5f * bf2f(pr.x >> 16) + 0.5f * r1;
        float y2 = 0.5f * bf2f(pr.y) + 0.5f * r2;
        float y3 = 0.5f * bf2f(pr.y >> 16) + 0.5f * r3;
        uint2 ou = { pk2(y0, y1), pk2(y2, y3) };
        *(uint2*)(xhat + rb + sl * 32 + colg * 4) = ou;
      }
    }
  }
}

// ---------------- K3: LayerNorm over x_hat rows (256 wide) ----------------
__global__ __launch_bounds__(256) void k_ln(
    const unsigned short* __restrict__ xh, const float* __restrict__ g,
    const float* __restrict__ bta, unsigned short* __restrict__ o)
{
  int row = blockIdx.x * 4 + (threadIdx.x >> 6);
  int lane = threadIdx.x & 63;
  size_t base = (size_t)row * 256 + lane * 4;
  uint2 raw = *(const uint2*)(xh + base);
  float v0 = bf2f(raw.x), v1 = bf2f(raw.x >> 16), v2 = bf2f(raw.y), v3 = bf2f(raw.y >> 16);
  float s1 = v0 + v1 + v2 + v3;
  float s2 = v0 * v0 + v1 * v1 + v2 * v2 + v3 * v3;
  #pragma unroll
  for (int off = 1; off < 64; off <<= 1) { s1 += __shfl_xor(s1, off); s2 += __shfl_xor(s2, off); }
  float mu = s1 * (1.f / 256.f);
  float var = s2 * (1.f / 256.f) - mu * mu;
  float rs = rsqrtf(var + 1e-5f);
  int c = lane * 4;
  float y0 = (v0 - mu) * rs * g[c] + bta[c];
  float y1 = (v1 - mu) * rs * g[c + 1] + bta[c + 1];
  float y2 = (v2 - mu) * rs * g[c + 2] + bta[c + 2];
  float y3 = (v3 - mu) * rs * g[c + 3] + bta[c + 3];
  uint2 ou = { pk2(y0, y1), pk2(y2, y3) };
  *(uint2*)(o + base) = ou;
}

// ---------------- K4: logits = LN(x_hat) @ Wo^T + bo -> out (B,L,V) f32 ----------------
__global__ __launch_bounds__(256) void k_logits(
    const unsigned short* __restrict__ ln, const float* __restrict__ Wo,
    const float* __restrict__ bo, float* __restrict__ out)
{
  __shared__ unsigned short As[64 * KPAD];
  __shared__ unsigned short Bs[64 * KPAD];
  const int tid = threadIdx.x, lane = tid & 63, wv = tid >> 6;
  const int m0 = blockIdx.y * 64, n0 = blockIdx.x * 64;
  const int sr = tid >> 2, skc = (tid & 3) * 8;
  const unsigned short* asrc = ln + (size_t)(m0 + sr) * 256 + skc;
  const int brow = n0 + sr;
  const bool bok = brow < V_SZ;
  const float* bsrc = Wo + (size_t)(bok ? brow : 0) * 256 + skc;

  f32x4 acc[4];
  #pragma unroll
  for (int i = 0; i < 4; ++i) acc[i] = 0.f;

  for (int ks = 0; ks < 8; ++ks) {
    __syncthreads();
    *(uint4*)&As[sr * KPAD + skc] = *(const uint4*)(asrc + ks * 32);
    uint4 ub = {0u, 0u, 0u, 0u};
    if (bok) {
      float4 q0 = *(const float4*)(bsrc + ks * 32);
      float4 q1 = *(const float4*)(bsrc + ks * 32 + 4);
      ub.x = pk2(q0.x, q0.y); ub.y = pk2(q0.z, q0.w);
      ub.z = pk2(q1.x, q1.y); ub.w = pk2(q1.z, q1.w);
    }
    *(uint4*)&Bs[sr * KPAD + skc] = ub;
    __syncthreads();
    bf16x8 af = *(const bf16x8*)&As[(wv * 16 + (lane & 15)) * KPAD + (lane >> 4) * 8];
    #pragma unroll
    for (int ns = 0; ns < 4; ++ns) {
      bf16x8 bfv = *(const bf16x8*)&Bs[(ns * 16 + (lane & 15)) * KPAD + (lane >> 4) * 8];
      acc[ns] = __builtin_amdgcn_mfma_f32_16x16x32_bf16(af, bfv, acc[ns], 0, 0, 0);
    }
  }
  const int mrow = m0 + wv * 16 + 4 * (lane >> 4);
  const int ncol = n0 + (lane & 15);
  #pragma unroll
  for (int ns = 0; ns < 4; ++ns) {
    int col = ncol + ns * 16;
    if (col < V_SZ) {
      float bv = bo[col];
      #pragma unroll
      for (int rr = 0; rr < 4; ++rr) {
        int row = mrow + rr;
        out[(size_t)(row & 15) * ((size_t)L_SEQ * V_SZ) + (size_t)(row >> 4) * V_SZ + col] =
            acc[ns][rr] + bv;
      }
    }
  }
}

extern "C" void kernel_launch(void* const* d_in, const int* in_sizes, int n_in,
                              void* d_out, int out_size, void* d_ws, size_t ws_size,
                              hipStream_t stream)
{
  const int*   tokens = (const int*)d_in[0];
  const float* emb    = (const float*)d_in[1];
  const float* Wih    = (const float*)d_in[2];
  const float* Whh    = (const float*)d_in[3];
  const float* bih    = (const float*)d_in[4];
  const float* bhh    = (const float*)d_in[5];
  const float* Wg     = (const float*)d_in[6];
  const float* bg     = (const float*)d_in[7];
  const float* Wx     = (const float*)d_in[8];
  const float* bx     = (const float*)d_in[9];
  const float* Wp     = (const float*)d_in[10];
  const float* bp     = (const float*)d_in[11];
  const float* lng    = (const float*)d_in[12];
  const float* lnb    = (const float*)d_in[13];
  const float* Wo     = (const float*)d_in[14];
  const float* bo     = (const float*)d_in[15];
  float* out = (float*)d_out;

  char* ws = (char*)d_ws;
  size_t off = 0;
  auto take = [&](size_t bytes) -> char* {
    char* p = ws + off;
    off += (bytes + 255) & ~(size_t)255;
    return p;
  };
  unsigned short* giT  = (unsigned short*)take((size_t)1024 * 1536 * 16 * 2); // 50.3 MB
  unsigned short* gS   = (unsigned short*)take((size_t)1024 * 16 * 256 * 2);  // 8.4 MB
  unsigned short* xS   = (unsigned short*)take((size_t)1024 * 16 * 256 * 2);
  unsigned short* xpS  = (unsigned short*)take((size_t)1024 * 16 * 256 * 2);
  unsigned short* xhat = (unsigned short*)take((size_t)1024 * 16 * 256 * 2);
  unsigned short* lnO  = (unsigned short*)take((size_t)1024 * 16 * 256 * 2);
  unsigned short* hbuf = (unsigned short*)take((size_t)2 * 16 * 512 * 2);
  int* bar             = (int*)take(256);
  if (off > ws_size) return;

  (void)hipMemsetAsync(bar, 0, 256, stream);

  k_gi<<<dim3(24, 256), 256, 0, stream>>>(tokens, emb, Wih, bih, giT);
  k_scan<<<192, 64, 0, stream>>>(giT, Whh, bhh, Wg, bg, Wx, bx, Wp, bp,
                                 gS, xS, xpS, xhat, hbuf, bar);
  k_ln<<<4096, 256, 0, stream>>>(xhat, lng, lnb, lnO);
  k_logits<<<dim3(157, 256), 256, 0, stream>>>(lnO, Wo, bo, out);
}

// Round 3
// 5690.060 us; speedup vs baseline: 1.7524x; 1.1189x over previous
//
#include <hip/hip_runtime.h>

#define L_SEQ 1024
#define B_SZ  16
#define D_SZ  512
#define V_SZ  10000

typedef __attribute__((ext_vector_type(8))) short bf16x8;
typedef __attribute__((ext_vector_type(4))) float f32x4;
typedef __attribute__((ext_vector_type(4))) unsigned int u32x4;
typedef __attribute__((ext_vector_type(2))) unsigned int u32x2;

__device__ __forceinline__ float bf2f(unsigned int u) {
  unsigned int x = (u & 0xffffu) << 16;
  return __builtin_bit_cast(float, x);
}
__device__ __forceinline__ unsigned short f2bf(float f) {
  unsigned int x = __builtin_bit_cast(unsigned int, f);
  x += 0x7fffu + ((x >> 16) & 1u);
  return (unsigned short)(x >> 16);
}
__device__ __forceinline__ unsigned int pk2(float lo, float hi) {
  return (unsigned int)f2bf(lo) | ((unsigned int)f2bf(hi) << 16);
}
__device__ __forceinline__ float sigm(float x) { return 1.f / (1.f + __expf(-x)); }
__device__ __forceinline__ float tanhfast(float x) {
  x = fminf(fmaxf(x, -15.f), 15.f);
  float e = __expf(2.f * x);
  return (e - 1.f) / (e + 1.f);
}

#define KPAD 40

// ---------------- K1: gi = gather(emb, tokens) @ W_ih^T + b_ih ----------------
__global__ __launch_bounds__(256) void k_gi(
    const int* __restrict__ tokens, const float* __restrict__ emb,
    const float* __restrict__ Wih, const float* __restrict__ bih,
    unsigned short* __restrict__ giT)
{
  __shared__ unsigned short As[64 * KPAD];
  __shared__ unsigned short Bs[64 * KPAD];
  const int tid = threadIdx.x, lane = tid & 63, wv = tid >> 6;
  const int m0 = blockIdx.y * 64, n0 = blockIdx.x * 64;
  const int sr = tid >> 2, skc = (tid & 3) * 8;
  const int grow = m0 + sr;
  const int tok = tokens[((grow & 15) << 10) + (grow >> 4)];
  const float* asrc = emb + (size_t)tok * 512 + skc;
  const float* bsrc = Wih + (size_t)(n0 + sr) * 512 + skc;

  f32x4 acc[4];
  #pragma unroll
  for (int i = 0; i < 4; ++i) acc[i] = 0.f;

  for (int ks = 0; ks < 16; ++ks) {
    __syncthreads();
    float4 a0 = *(const float4*)(asrc + ks * 32);
    float4 a1 = *(const float4*)(asrc + ks * 32 + 4);
    float4 q0 = *(const float4*)(bsrc + ks * 32);
    float4 q1 = *(const float4*)(bsrc + ks * 32 + 4);
    uint4 ua = { pk2(a0.x, a0.y), pk2(a0.z, a0.w), pk2(a1.x, a1.y), pk2(a1.z, a1.w) };
    uint4 ub = { pk2(q0.x, q0.y), pk2(q0.z, q0.w), pk2(q1.x, q1.y), pk2(q1.z, q1.w) };
    *(uint4*)&As[sr * KPAD + skc] = ua;
    *(uint4*)&Bs[sr * KPAD + skc] = ub;
    __syncthreads();
    bf16x8 af = *(const bf16x8*)&As[(wv * 16 + (lane & 15)) * KPAD + (lane >> 4) * 8];
    #pragma unroll
    for (int ns = 0; ns < 4; ++ns) {
      bf16x8 bfv = *(const bf16x8*)&Bs[(ns * 16 + (lane & 15)) * KPAD + (lane >> 4) * 8];
      acc[ns] = __builtin_amdgcn_mfma_f32_16x16x32_bf16(af, bfv, acc[ns], 0, 0, 0);
    }
  }
  const int mrow = m0 + wv * 16 + 4 * (lane >> 4);
  const int ncol = n0 + (lane & 15);
  #pragma unroll
  for (int ns = 0; ns < 4; ++ns) {
    int col = ncol + ns * 16;
    float bv = bih[col];
    #pragma unroll
    for (int rr = 0; rr < 4; ++rr) {
      int row = mrow + rr;
      giT[((size_t)(row >> 4) * 1536 + col) * 16 + (row & 15)] = f2bf(acc[ns][rr] + bv);
    }
  }
}

// ---------------- K2: persistent fused scan, tagged-payload sync ----------------
// h qword: {pk2(h[2P],h[2P+1]), tag=t+1} at hq[(t&1)*4096 + b*256 + P], P=dim/2.
// stream record (16B): {g-pair, x-pair, xp-pair, tag=t+1} at recS[((t*16+b)*128 + c)],
//   c = column-pair index 0..127.
// No flags, no drains: the tag IS the release; poll returns the data itself.
__global__ __launch_bounds__(64) void k_scan(
    const unsigned short* __restrict__ giT,
    const float* __restrict__ Whh, const float* __restrict__ bhh,
    const float* __restrict__ Wg, const float* __restrict__ bg,
    const float* __restrict__ Wx, const float* __restrict__ bx,
    const float* __restrict__ Wp, const float* __restrict__ bp,
    u32x4* __restrict__ recS, unsigned short* __restrict__ xhat,
    unsigned long long* __restrict__ hq)
{
  __shared__ char smem[53248];
  const int lane = threadIdx.x;
  const int wid = blockIdx.x;

  if (wid < 64) {
    unsigned short* wlds = (unsigned short*)smem;  // 48 x 520 bf16
    float* scr = (float*)(smem + 49920);           // [16][48] viewed as 3 16x16 tiles
    const int w = wid;

    for (int row = 0; row < 48; ++row) {
      const float* src = nullptr;
      if (row < 24)                   src = Whh + (size_t)((row >> 3) * 512 + w * 8 + (row & 7)) * 512;
      else if (row >= 32 && row < 36) src = Wg + (size_t)(w * 4 + row - 32) * 512;
      else if (row >= 36 && row < 40) src = Wx + (size_t)(w * 4 + row - 36) * 512;
      else if (row >= 40 && row < 44) src = Wp + (size_t)(w * 4 + row - 40) * 512;
      uint4 u = {0u, 0u, 0u, 0u};
      if (src) {
        float4 p0 = *(const float4*)(src + lane * 8);
        float4 p1 = *(const float4*)(src + lane * 8 + 4);
        u.x = pk2(p0.x, p0.y); u.y = pk2(p0.z, p0.w);
        u.z = pk2(p1.x, p1.y); u.w = pk2(p1.z, p1.w);
      }
      *(uint4*)&wlds[row * 520 + lane * 8] = u;
    }
    __syncthreads();

    const int b_ = lane & 15;
    const int hi = lane >> 4;
    const int dd1 = hi * 2, dd2 = hi * 2 + 1;
    const float bhr1 = bhh[w * 8 + dd1], bhz1 = bhh[512 + w * 8 + dd1], bhn1 = bhh[1024 + w * 8 + dd1];
    const float bhr2 = bhh[w * 8 + dd2], bhz2 = bhh[512 + w * 8 + dd2], bhn2 = bhh[1024 + w * 8 + dd2];
    const float bgv0 = bg[w * 4 + 2 * (hi & 1)], bgv1 = bg[w * 4 + 2 * (hi & 1) + 1];
    const float bxv0 = bx[w * 4 + 2 * (hi & 1)], bxv1 = bx[w * 4 + 2 * (hi & 1) + 1];
    const float bpv0 = bp[w * 4 + 2 * (hi & 1)], bpv1 = bp[w * 4 + 2 * (hi & 1) + 1];
    float hprev1 = 0.f, hprev2 = 0.f;

    #pragma unroll 1
    for (int t = 0; t <= L_SEQ; ++t) {
      float gir1 = 0, giz1 = 0, gin1 = 0, gir2 = 0, giz2 = 0, gin2 = 0;
      if (t < L_SEQ) {
        const unsigned short* gib = giT + (size_t)t * 1536 * 16 + b_;
        gir1 = bf2f(gib[(size_t)(w * 8 + dd1) * 16]);
        giz1 = bf2f(gib[(size_t)(512 + w * 8 + dd1) * 16]);
        gin1 = bf2f(gib[(size_t)(1024 + w * 8 + dd1) * 16]);
        gir2 = bf2f(gib[(size_t)(w * 8 + dd2) * 16]);
        giz2 = bf2f(gib[(size_t)(512 + w * 8 + dd2) * 16]);
        gin2 = bf2f(gib[(size_t)(1024 + w * 8 + dd2) * 16]);
      }
      bf16x8 afr[16];
      if (t > 0) {
        // poll h(t-1): tag == t, payload arrives with the successful poll
        const unsigned long long* hsrc = hq + (size_t)((t - 1) & 1) * 4096 + (size_t)b_ * 256 + hi * 4;
        const unsigned int tagv = (unsigned int)t;
        u32x4 q0[16], q1[16];
        int spins = 0;
        for (;;) {
          #pragma unroll
          for (int kk = 0; kk < 16; ++kk) {
            asm volatile(
              "global_load_dwordx4 %0, %2, off offset:%3 sc0 sc1\n\t"
              "global_load_dwordx4 %1, %2, off offset:%4 sc0 sc1"
              : "=&v"(q0[kk]), "=&v"(q1[kk])
              : "v"(hsrc), "i"(kk * 128), "i"(kk * 128 + 16)
              : "memory");
          }
          asm volatile("s_waitcnt vmcnt(0)" ::: "memory");
          bool ok = true;
          #pragma unroll
          for (int kk = 0; kk < 16; ++kk) {
            ok = ok && (q0[kk].y == tagv) && (q0[kk].w == tagv)
                    && (q1[kk].y == tagv) && (q1[kk].w == tagv);
          }
          if (__all(ok)) break;
          if (++spins > 150000) break;
        }
        #pragma unroll
        for (int kk = 0; kk < 16; ++kk) {
          u32x4 f = { q0[kk].x, q0[kk].z, q1[kk].x, q1[kk].z };
          afr[kk] = __builtin_bit_cast(bf16x8, f);
        }
      } else {
        bf16x8 z = {0, 0, 0, 0, 0, 0, 0, 0};
        #pragma unroll
        for (int kk = 0; kk < 16; ++kk) afr[kk] = z;
      }
      f32x4 a0 = 0.f, a1 = 0.f, a2 = 0.f;
      const unsigned short* bbase = wlds + (size_t)b_ * 520 + hi * 8;
      #pragma unroll
      for (int kk = 0; kk < 16; ++kk) {
        bf16x8 b0 = *(const bf16x8*)(bbase + kk * 32);
        bf16x8 b1 = *(const bf16x8*)(bbase + 16 * 520 + kk * 32);
        bf16x8 b2 = *(const bf16x8*)(bbase + 32 * 520 + kk * 32);
        a0 = __builtin_amdgcn_mfma_f32_16x16x32_bf16(afr[kk], b0, a0, 0, 0, 0);
        a1 = __builtin_amdgcn_mfma_f32_16x16x32_bf16(afr[kk], b1, a1, 0, 0, 0);
        a2 = __builtin_amdgcn_mfma_f32_16x16x32_bf16(afr[kk], b2, a2, 0, 0, 0);
      }
      {
        int m = 4 * hi;
        #pragma unroll
        for (int rr = 0; rr < 4; ++rr) {
          scr[(m + rr) * 16 + b_] = a0[rr];
          scr[256 + (m + rr) * 16 + b_] = a1[rr];
          scr[512 + (m + rr) * 16 + b_] = a2[rr];
        }
      }
      __syncthreads();
      if (t < L_SEQ) {
        float r1 = sigm(scr[b_ * 16 + dd1] + gir1 + bhr1);
        float z1 = sigm(scr[b_ * 16 + 8 + dd1] + giz1 + bhz1);
        float n1 = tanhfast(gin1 + r1 * (scr[256 + b_ * 16 + dd1] + bhn1));
        float h1 = (1.f - z1) * n1 + z1 * hprev1; hprev1 = h1;
        float r2 = sigm(scr[b_ * 16 + dd2] + gir2 + bhr2);
        float z2 = sigm(scr[b_ * 16 + 8 + dd2] + giz2 + bhz2);
        float n2 = tanhfast(gin2 + r2 * (scr[256 + b_ * 16 + dd2] + bhn2));
        float h2 = (1.f - z2) * n2 + z2 * hprev2; hprev2 = h2;
        // tagged h store: one 8B qword per lane, fire-and-forget
        u32x2 hv = { pk2(h1, h2), (unsigned int)(t + 1) };
        unsigned long long* hdst = hq + (size_t)(t & 1) * 4096 + (size_t)b_ * 256 + w * 4 + hi;
        asm volatile("global_store_dwordx2 %0, %1, off sc0 sc1" :: "v"(hdst), "v"(hv) : "memory");
      }
      if (t > 0 && lane < 32) {
        // tagged stream record for step t-1: one 16B dwordx4 per lane
        const int bb = lane & 15, cp = lane >> 4;
        float g0 = scr[512 + bb * 16 + 2 * cp],     g1 = scr[512 + bb * 16 + 2 * cp + 1];
        float x0 = scr[512 + bb * 16 + 4 + 2 * cp], x1 = scr[512 + bb * 16 + 4 + 2 * cp + 1];
        float p0 = scr[512 + bb * 16 + 8 + 2 * cp], p1 = scr[512 + bb * 16 + 8 + 2 * cp + 1];
        // scr[512..] holds raw MFMA output (no bias); add biases here
        g0 += bg[w * 4 + 2 * cp]; g1 += bg[w * 4 + 2 * cp + 1];
        x0 += bx[w * 4 + 2 * cp]; x1 += bx[w * 4 + 2 * cp + 1];
        p0 += bp[w * 4 + 2 * cp]; p1 += bp[w * 4 + 2 * cp + 1];
        u32x4 rec = { pk2(g0, g1), pk2(x0, x1), pk2(p0, p1), (unsigned int)t };
        u32x4* rdst = recS + ((size_t)(t - 1) * 16 + bb) * 128 + w * 2 + cp;
        asm volatile("global_store_dwordx4 %0, %1, off sc0 sc1" :: "v"(rdst), "v"(rec) : "memory");
      }
      __syncthreads();
    }
  } else {
    float* Msh = (float*)smem;  // [256][32] f32
    const int id = wid - 64;
    const int b = id >> 3, sl = id & 7;
    const int colg = lane & 7, dgs = lane >> 3;
    for (int i = lane * 4; i < 8192; i += 256) *(float4*)&Msh[i] = float4{0.f, 0.f, 0.f, 0.f};
    __syncthreads();
    #pragma unroll 1
    for (int t = 0; t < L_SEQ; ++t) {
      const u32x4* rp = recS + ((size_t)t * 16 + b) * 128 + 2 * lane;
      const unsigned int tagv = (unsigned int)(t + 1);
      u32x4 r0, r1;
      int spins = 0;
      for (;;) {
        asm volatile(
          "global_load_dwordx4 %0, %2, off sc0 sc1\n\t"
          "global_load_dwordx4 %1, %2, off offset:16 sc0 sc1\n\t"
          "s_waitcnt vmcnt(0)"
          : "=&v"(r0), "=&v"(r1) : "v"(rp) : "memory");
        if (__all((r0.w == tagv) && (r1.w == tagv))) break;
        if (++spins > 150000) break;
      }
      // redistribute via shuffles: lane L holds cols [4L, 4L+4)
      const int lx = sl * 8 + colg;
      unsigned int xa = (unsigned int)__shfl((int)r0.y, lx);
      unsigned int xb = (unsigned int)__shfl((int)r1.y, lx);
      unsigned int pa = (unsigned int)__shfl((int)r0.z, lx);
      unsigned int pb = (unsigned int)__shfl((int)r1.z, lx);
      float xv0 = bf2f(xa), xv1 = bf2f(xa >> 16), xv2 = bf2f(xb), xv3 = bf2f(xb >> 16);
      float r0a = 0, r1a = 0, r2a = 0, r3a = 0;
      #pragma unroll
      for (int ic = 0; ic < 8; ++ic) {
        const int ls = dgs * 8 + ic;
        unsigned int ga = (unsigned int)__shfl((int)r0.x, ls);
        unsigned int gb = (unsigned int)__shfl((int)r1.x, ls);
        float gj[4] = { bf2f(ga), bf2f(ga >> 16), bf2f(gb), bf2f(gb >> 16) };
        int dg = dgs * 32 + ic * 4;
        #pragma unroll
        for (int j = 0; j < 4; ++j) {
          float4* mp = (float4*)&Msh[(dg + j) * 32 + colg * 4];
          float4 m = *mp;
          r0a += gj[j] * m.x; r1a += gj[j] * m.y; r2a += gj[j] * m.z; r3a += gj[j] * m.w;
          m.x += gj[j] * xv0; m.y += gj[j] * xv1; m.z += gj[j] * xv2; m.w += gj[j] * xv3;
          *mp = m;
        }
      }
      #pragma unroll
      for (int off = 8; off < 64; off <<= 1) {
        r0a += __shfl_xor(r0a, off); r1a += __shfl_xor(r1a, off);
        r2a += __shfl_xor(r2a, off); r3a += __shfl_xor(r3a, off);
      }
      if (dgs == 0) {
        float y0 = 0.5f * bf2f(pa) + 0.5f * r0a;
        float y1 = 0.5f * bf2f(pa >> 16) + 0.5f * r1a;
        float y2 = 0.5f * bf2f(pb) + 0.5f * r2a;
        float y3 = 0.5f * bf2f(pb >> 16) + 0.5f * r3a;
        uint2 ou = { pk2(y0, y1), pk2(y2, y3) };
        *(uint2*)(xhat + ((size_t)t * 16 + b) * 256 + sl * 32 + colg * 4) = ou;
      }
    }
  }
}

// ---------------- K3: LayerNorm in place over x_hat rows ----------------
__global__ __launch_bounds__(256) void k_ln(
    unsigned short* xh, const float* __restrict__ g, const float* __restrict__ bta)
{
  int row = blockIdx.x * 4 + (threadIdx.x >> 6);
  int lane = threadIdx.x & 63;
  size_t base = (size_t)row * 256 + lane * 4;
  uint2 raw = *(const uint2*)(xh + base);
  float v0 = bf2f(raw.x), v1 = bf2f(raw.x >> 16), v2 = bf2f(raw.y), v3 = bf2f(raw.y >> 16);
  float s1 = v0 + v1 + v2 + v3;
  float s2 = v0 * v0 + v1 * v1 + v2 * v2 + v3 * v3;
  #pragma unroll
  for (int off = 1; off < 64; off <<= 1) { s1 += __shfl_xor(s1, off); s2 += __shfl_xor(s2, off); }
  float mu = s1 * (1.f / 256.f);
  float var = s2 * (1.f / 256.f) - mu * mu;
  float rs = rsqrtf(var + 1e-5f);
  int c = lane * 4;
  float y0 = (v0 - mu) * rs * g[c] + bta[c];
  float y1 = (v1 - mu) * rs * g[c + 1] + bta[c + 1];
  float y2 = (v2 - mu) * rs * g[c + 2] + bta[c + 2];
  float y3 = (v3 - mu) * rs * g[c + 3] + bta[c + 3];
  uint2 ou = { pk2(y0, y1), pk2(y2, y3) };
  *(uint2*)(xh + base) = ou;
}

// ---------------- K4: logits = LN(x_hat) @ Wo^T + bo -> out (B,L,V) f32 ----------------
__global__ __launch_bounds__(256) void k_logits(
    const unsigned short* __restrict__ ln, const float* __restrict__ Wo,
    const float* __restrict__ bo, float* __restrict__ out)
{
  __shared__ unsigned short As[64 * KPAD];
  __shared__ unsigned short Bs[64 * KPAD];
  const int tid = threadIdx.x, lane = tid & 63, wv = tid >> 6;
  const int m0 = blockIdx.y * 64, n0 = blockIdx.x * 64;
  const int sr = tid >> 2, skc = (tid & 3) * 8;
  const unsigned short* asrc = ln + (size_t)(m0 + sr) * 256 + skc;
  const int brow = n0 + sr;
  const bool bok = brow < V_SZ;
  const float* bsrc = Wo + (size_t)(bok ? brow : 0) * 256 + skc;

  f32x4 acc[4];
  #pragma unroll
  for (int i = 0; i < 4; ++i) acc[i] = 0.f;

  for (int ks = 0; ks < 8; ++ks) {
    __syncthreads();
    *(uint4*)&As[sr * KPAD + skc] = *(const uint4*)(asrc + ks * 32);
    uint4 ub = {0u, 0u, 0u, 0u};
    if (bok) {
      float4 q0 = *(const float4*)(bsrc + ks * 32);
      float4 q1 = *(const float4*)(bsrc + ks * 32 + 4);
      ub.x = pk2(q0.x, q0.y); ub.y = pk2(q0.z, q0.w);
      ub.z = pk2(q1.x, q1.y); ub.w = pk2(q1.z, q1.w);
    }
    *(uint4*)&Bs[sr * KPAD + skc] = ub;
    __syncthreads();
    bf16x8 af = *(const bf16x8*)&As[(wv * 16 + (lane & 15)) * KPAD + (lane >> 4) * 8];
    #pragma unroll
    for (int ns = 0; ns < 4; ++ns) {
      bf16x8 bfv = *(const bf16x8*)&Bs[(ns * 16 + (lane & 15)) * KPAD + (lane >> 4) * 8];
      acc[ns] = __builtin_amdgcn_mfma_f32_16x16x32_bf16(af, bfv, acc[ns], 0, 0, 0);
    }
  }
  const int mrow = m0 + wv * 16 + 4 * (lane >> 4);
  const int ncol = n0 + (lane & 15);
  #pragma unroll
  for (int ns = 0; ns < 4; ++ns) {
    int col = ncol + ns * 16;
    if (col < V_SZ) {
      float bv = bo[col];
      #pragma unroll
      for (int rr = 0; rr < 4; ++rr) {
        int row = mrow + rr;
        out[(size_t)(row & 15) * ((size_t)L_SEQ * V_SZ) + (size_t)(row >> 4) * V_SZ + col] =
            acc[ns][rr] + bv;
      }
    }
  }
}

extern "C" void kernel_launch(void* const* d_in, const int* in_sizes, int n_in,
                              void* d_out, int out_size, void* d_ws, size_t ws_size,
                              hipStream_t stream)
{
  const int*   tokens = (const int*)d_in[0];
  const float* emb    = (const float*)d_in[1];
  const float* Wih    = (const float*)d_in[2];
  const float* Whh    = (const float*)d_in[3];
  const float* bih    = (const float*)d_in[4];
  const float* bhh    = (const float*)d_in[5];
  const float* Wg     = (const float*)d_in[6];
  const float* bg     = (const float*)d_in[7];
  const float* Wx     = (const float*)d_in[8];
  const float* bx     = (const float*)d_in[9];
  const float* Wp     = (const float*)d_in[10];
  const float* bp     = (const float*)d_in[11];
  const float* lng    = (const float*)d_in[12];
  const float* lnb    = (const float*)d_in[13];
  const float* Wo     = (const float*)d_in[14];
  const float* bo     = (const float*)d_in[15];
  float* out = (float*)d_out;

  char* ws = (char*)d_ws;
  size_t off = 0;
  auto take = [&](size_t bytes) -> char* {
    char* p = ws + off;
    off += (bytes + 255) & ~(size_t)255;
    return p;
  };
  unsigned short* giT      = (unsigned short*)take((size_t)1024 * 1536 * 16 * 2);  // 50.33 MB
  u32x4* recS              = (u32x4*)take((size_t)1024 * 16 * 128 * 16);           // 33.55 MB
  unsigned short* xhat     = (unsigned short*)take((size_t)1024 * 16 * 256 * 2);   // 8.39 MB
  unsigned long long* hq   = (unsigned long long*)take((size_t)2 * 4096 * 8);      // 64 KB
  if (off > ws_size) return;

  // zero all tag-bearing buffers每 call: stale tags can never false-trigger
  (void)hipMemsetAsync(recS, 0, (size_t)1024 * 16 * 128 * 16, stream);
  (void)hipMemsetAsync(hq, 0, (size_t)2 * 4096 * 8, stream);

  k_gi<<<dim3(24, 256), 256, 0, stream>>>(tokens, emb, Wih, bih, giT);
  k_scan<<<192, 64, 0, stream>>>(giT, Whh, bhh, Wg, bg, Wx, bx, Wp, bp,
                                 recS, xhat, hq);
  k_ln<<<4096, 256, 0, stream>>>(xhat, lng, lnb);
  k_logits<<<dim3(157, 256), 256, 0, stream>>>(xhat, Wo, bo, out);
}

// Round 4
// 4746.581 us; speedup vs baseline: 2.1007x; 1.1988x over previous
//
#include <hip/hip_runtime.h>

#define L_SEQ 1024
#define B_SZ  16
#define D_SZ  512
#define V_SZ  10000
#define HQ_SLOTS 8

typedef __attribute__((ext_vector_type(8))) short bf16x8;
typedef __attribute__((ext_vector_type(4))) float f32x4;
typedef __attribute__((ext_vector_type(4))) unsigned int u32x4;
typedef __attribute__((ext_vector_type(2))) unsigned int u32x2;

__device__ __forceinline__ float bf2f(unsigned int u) {
  unsigned int x = (u & 0xffffu) << 16;
  return __builtin_bit_cast(float, x);
}
__device__ __forceinline__ unsigned short f2bf(float f) {
  unsigned int x = __builtin_bit_cast(unsigned int, f);
  x += 0x7fffu + ((x >> 16) & 1u);
  return (unsigned short)(x >> 16);
}
__device__ __forceinline__ unsigned int pk2(float lo, float hi) {
  return (unsigned int)f2bf(lo) | ((unsigned int)f2bf(hi) << 16);
}
__device__ __forceinline__ float sigm(float x) { return 1.f / (1.f + __expf(-x)); }
__device__ __forceinline__ float tanhfast(float x) {
  x = fminf(fmaxf(x, -15.f), 15.f);
  float e = __expf(2.f * x);
  return (e - 1.f) / (e + 1.f);
}

#define KPAD 40

// ---------------- K1: gi = gather(emb, tokens) @ W_ih^T + b_ih ----------------
__global__ __launch_bounds__(256) void k_gi(
    const int* __restrict__ tokens, const float* __restrict__ emb,
    const float* __restrict__ Wih, const float* __restrict__ bih,
    unsigned short* __restrict__ giT)
{
  __shared__ unsigned short As[64 * KPAD];
  __shared__ unsigned short Bs[64 * KPAD];
  const int tid = threadIdx.x, lane = tid & 63, wv = tid >> 6;
  const int m0 = blockIdx.y * 64, n0 = blockIdx.x * 64;
  const int sr = tid >> 2, skc = (tid & 3) * 8;
  const int grow = m0 + sr;
  const int tok = tokens[((grow & 15) << 10) + (grow >> 4)];
  const float* asrc = emb + (size_t)tok * 512 + skc;
  const float* bsrc = Wih + (size_t)(n0 + sr) * 512 + skc;

  f32x4 acc[4];
  #pragma unroll
  for (int i = 0; i < 4; ++i) acc[i] = 0.f;

  for (int ks = 0; ks < 16; ++ks) {
    __syncthreads();
    float4 a0 = *(const float4*)(asrc + ks * 32);
    float4 a1 = *(const float4*)(asrc + ks * 32 + 4);
    float4 q0 = *(const float4*)(bsrc + ks * 32);
    float4 q1 = *(const float4*)(bsrc + ks * 32 + 4);
    uint4 ua = { pk2(a0.x, a0.y), pk2(a0.z, a0.w), pk2(a1.x, a1.y), pk2(a1.z, a1.w) };
    uint4 ub = { pk2(q0.x, q0.y), pk2(q0.z, q0.w), pk2(q1.x, q1.y), pk2(q1.z, q1.w) };
    *(uint4*)&As[sr * KPAD + skc] = ua;
    *(uint4*)&Bs[sr * KPAD + skc] = ub;
    __syncthreads();
    bf16x8 af = *(const bf16x8*)&As[(wv * 16 + (lane & 15)) * KPAD + (lane >> 4) * 8];
    #pragma unroll
    for (int ns = 0; ns < 4; ++ns) {
      bf16x8 bfv = *(const bf16x8*)&Bs[(ns * 16 + (lane & 15)) * KPAD + (lane >> 4) * 8];
      acc[ns] = __builtin_amdgcn_mfma_f32_16x16x32_bf16(af, bfv, acc[ns], 0, 0, 0);
    }
  }
  const int mrow = m0 + wv * 16 + 4 * (lane >> 4);
  const int ncol = n0 + (lane & 15);
  #pragma unroll
  for (int ns = 0; ns < 4; ++ns) {
    int col = ncol + ns * 16;
    float bv = bih[col];
    #pragma unroll
    for (int rr = 0; rr < 4; ++rr) {
      int row = mrow + rr;
      giT[((size_t)(row >> 4) * 1536 + col) * 16 + (row & 15)] = f2bf(acc[ns][rr] + bv);
    }
  }
}

// ---------------- K2: persistent fused scan ----------------
// blocks 0..15 : gh producers (WG w owns h dims [32w,32w+32)). Whh rows in LDS.
//   Per step: 4 waves quarter-poll tagged h(t-1) (4KB/wave) -> LDS hsh -> sync ->
//   A-frags from LDS -> 6 MFMA tiles -> GRU pointwise -> tagged h(t) store.
// blocks 16..23: gxp producers (WG u owns cols [32u,32u+32) of g/x/xp). Poll h(t),
//   MFMA, emit tagged 16B records {g,x,xp,tag}. Off the h critical path.
// blocks 24..55: consumers: 4 independent waves each own M[b][:, 32-col slice] in
//   LDS; poll records, retr + Hebbian update + x_hat.
__global__ __launch_bounds__(256) void k_scan(
    const unsigned short* __restrict__ giT,
    const float* __restrict__ Whh, const float* __restrict__ bhh,
    const float* __restrict__ Wg, const float* __restrict__ bg,
    const float* __restrict__ Wx, const float* __restrict__ bx,
    const float* __restrict__ Wp, const float* __restrict__ bp,
    u32x4* __restrict__ recS, unsigned short* __restrict__ xhat,
    unsigned long long* __restrict__ hq)
{
  __shared__ char smem[131072];
  const int tid = threadIdx.x;
  const int lane = tid & 63, v = tid >> 6;
  const int wid = blockIdx.x;

  if (wid < 24) {
    const bool isGH = (wid < 16);
    const int w = isGH ? wid : (wid - 16);
    unsigned short* wlds = (unsigned short*)smem;                // 96 x 528 u16 = 101376B
    float* scr = (float*)(smem + 101376);                        // 6 x 16 x 16 f32 = 6144B
    unsigned int* hsh = (unsigned int*)(smem + 101376 + 6144);   // 16 x 264 u32 = 16896B

    // stage weights (rows: gh = gate*32+ld of Whh; gxp = {g,x,p}*32+lc)
    for (int row = v; row < 96; row += 4) {
      const float* src;
      if (isGH) {
        src = Whh + ((size_t)(row >> 5) * 512 + w * 32 + (row & 31)) * 512;
      } else {
        int m = row >> 5;
        const float* Wm = (m == 0) ? Wg : (m == 1) ? Wx : Wp;
        src = Wm + (size_t)(w * 32 + (row & 31)) * 512;
      }
      float4 p0 = *(const float4*)(src + lane * 8);
      float4 p1 = *(const float4*)(src + lane * 8 + 4);
      uint4 uu = { pk2(p0.x, p0.y), pk2(p0.z, p0.w), pk2(p1.x, p1.y), pk2(p1.z, p1.w) };
      *(uint4*)&wlds[row * 528 + lane * 8] = uu;
    }
    __syncthreads();

    const int b_ = lane & 15;
    const int c_ = lane >> 4;
    const int hi = lane >> 4;
    const int bb = tid & 15, dp = tid >> 4;          // tail thread mapping
    const int nt = (v < 2) ? 2 : 1;
    const int T0 = (v < 2) ? 2 * v : 2 + v;          // v=2 -> tile4, v=3 -> tile5

    float bhr1 = 0, bhz1 = 0, bhn1 = 0, bhr2 = 0, bhz2 = 0, bhn2 = 0;
    float bgc0 = 0, bgc1 = 0, bxc0 = 0, bxc1 = 0, bpc0 = 0, bpc1 = 0;
    float hprev1 = 0.f, hprev2 = 0.f;
    int d0 = w * 32 + 2 * dp, d1 = d0 + 1;
    if (isGH) {
      bhr1 = bhh[d0]; bhz1 = bhh[512 + d0]; bhn1 = bhh[1024 + d0];
      bhr2 = bhh[d1]; bhz2 = bhh[512 + d1]; bhn2 = bhh[1024 + d1];
    } else {
      bgc0 = bg[d0]; bgc1 = bg[d1];
      bxc0 = bx[d0]; bxc1 = bx[d1];
      bpc0 = bp[d0]; bpc1 = bp[d1];
    }

    // gi double-buffer (gh only): current regs + next-step prefetch
    float gir1 = 0, giz1 = 0, gin1 = 0, gir2 = 0, giz2 = 0, gin2 = 0;
    float nir1 = 0, niz1 = 0, nin1 = 0, nir2 = 0, niz2 = 0, nin2 = 0;
    if (isGH) {
      const unsigned short* gib = giT + bb;
      gir1 = bf2f(gib[(size_t)d0 * 16]);
      giz1 = bf2f(gib[(size_t)(512 + d0) * 16]);
      gin1 = bf2f(gib[(size_t)(1024 + d0) * 16]);
      gir2 = bf2f(gib[(size_t)d1 * 16]);
      giz2 = bf2f(gib[(size_t)(512 + d1) * 16]);
      gin2 = bf2f(gib[(size_t)(1024 + d1) * 16]);
    }

    #pragma unroll 1
    for (int t = 0; t < L_SEQ; ++t) {
      const int pt = isGH ? (t - 1) : t;            // h step consumed this iter
      const bool doPoll = (!isGH) || (t > 0);
      bf16x8 afr[16];
      if (doPoll) {
        const unsigned long long* hsrc = hq + (size_t)(pt & (HQ_SLOTS - 1)) * 4096
                                            + (size_t)b_ * 256 + 64 * v + 16 * c_;
        const unsigned int tv = (unsigned int)(pt + 1);
        u32x4 q0, q1, q2, q3, q4, q5, q6, q7;
        int spins = 0;
        for (;;) {
          asm volatile(
            "global_load_dwordx4 %0, %8, off sc0 sc1\n\t"
            "global_load_dwordx4 %1, %8, off offset:16 sc0 sc1\n\t"
            "global_load_dwordx4 %2, %8, off offset:32 sc0 sc1\n\t"
            "global_load_dwordx4 %3, %8, off offset:48 sc0 sc1\n\t"
            "global_load_dwordx4 %4, %8, off offset:64 sc0 sc1\n\t"
            "global_load_dwordx4 %5, %8, off offset:80 sc0 sc1\n\t"
            "global_load_dwordx4 %6, %8, off offset:96 sc0 sc1\n\t"
            "global_load_dwordx4 %7, %8, off offset:112 sc0 sc1\n\t"
            "s_waitcnt vmcnt(0)"
            : "=&v"(q0), "=&v"(q1), "=&v"(q2), "=&v"(q3),
              "=&v"(q4), "=&v"(q5), "=&v"(q6), "=&v"(q7)
            : "v"(hsrc) : "memory");
          bool ok = (q0.y == tv) && (q0.w == tv) && (q1.y == tv) && (q1.w == tv)
                 && (q2.y == tv) && (q2.w == tv) && (q3.y == tv) && (q3.w == tv)
                 && (q4.y == tv) && (q4.w == tv) && (q5.y == tv) && (q5.w == tv)
                 && (q6.y == tv) && (q6.w == tv) && (q7.y == tv) && (q7.w == tv);
          if (__all(ok)) break;
          if (++spins > 2000000) break;
        }
        // stage payload into LDS (chunk j stored at position j^c_ for bank spread)
        const int base = b_ * 264 + 64 * v + 16 * c_;
        u32x4 w0 = { q0.x, q0.z, q1.x, q1.z };
        u32x4 w1 = { q2.x, q2.z, q3.x, q3.z };
        u32x4 w2 = { q4.x, q4.z, q5.x, q5.z };
        u32x4 w3 = { q6.x, q6.z, q7.x, q7.z };
        *(u32x4*)&hsh[base + 4 * (0 ^ c_)] = w0;
        *(u32x4*)&hsh[base + 4 * (1 ^ c_)] = w1;
        *(u32x4*)&hsh[base + 4 * (2 ^ c_)] = w2;
        *(u32x4*)&hsh[base + 4 * (3 ^ c_)] = w3;
        __syncthreads();  // A: all quarters staged
        #pragma unroll
        for (int kk = 0; kk < 16; ++kk) {
          int idx = b_ * 264 + 64 * (kk >> 2) + 16 * (kk & 3) + 4 * (hi ^ (kk & 3));
          afr[kk] = *(const bf16x8*)&hsh[idx];
        }
      } else {
        bf16x8 z = {0, 0, 0, 0, 0, 0, 0, 0};
        #pragma unroll
        for (int kk = 0; kk < 16; ++kk) afr[kk] = z;
      }

      f32x4 accA = 0.f, accB = 0.f;
      const unsigned short* brow0 = wlds + (size_t)(T0 * 16 + b_) * 528 + hi * 8;
      if (nt == 2) {
        const unsigned short* brow1 = brow0 + 16 * 528;
        #pragma unroll
        for (int kk = 0; kk < 16; ++kk) {
          bf16x8 bf0 = *(const bf16x8*)(brow0 + kk * 32);
          bf16x8 bf1 = *(const bf16x8*)(brow1 + kk * 32);
          accA = __builtin_amdgcn_mfma_f32_16x16x32_bf16(afr[kk], bf0, accA, 0, 0, 0);
          accB = __builtin_amdgcn_mfma_f32_16x16x32_bf16(afr[kk], bf1, accB, 0, 0, 0);
        }
      } else {
        #pragma unroll
        for (int kk = 0; kk < 16; ++kk) {
          bf16x8 bf0 = *(const bf16x8*)(brow0 + kk * 32);
          accA = __builtin_amdgcn_mfma_f32_16x16x32_bf16(afr[kk], bf0, accA, 0, 0, 0);
        }
      }

      if (isGH && (t + 1 < L_SEQ)) {  // prefetch gi(t+1); hides under scr/sync/pointwise
        const unsigned short* gib = giT + (size_t)(t + 1) * 1536 * 16 + bb;
        nir1 = bf2f(gib[(size_t)d0 * 16]);
        niz1 = bf2f(gib[(size_t)(512 + d0) * 16]);
        nin1 = bf2f(gib[(size_t)(1024 + d0) * 16]);
        nir2 = bf2f(gib[(size_t)d1 * 16]);
        niz2 = bf2f(gib[(size_t)(512 + d1) * 16]);
        nin2 = bf2f(gib[(size_t)(1024 + d1) * 16]);
      }

      {
        int m4 = 4 * hi;
        #pragma unroll
        for (int rr = 0; rr < 4; ++rr) {
          scr[T0 * 256 + (m4 + rr) * 16 + b_] = accA[rr];
        }
        if (nt == 2) {
          #pragma unroll
          for (int rr = 0; rr < 4; ++rr) {
            scr[(T0 + 1) * 256 + (m4 + rr) * 16 + b_] = accB[rr];
          }
        }
      }
      __syncthreads();  // B: scr ready

      if (isGH) {
        const int Tr = dp >> 3, j0 = (2 * dp) & 15;
        float ar1 = scr[Tr * 256 + bb * 16 + j0],       ar2 = scr[Tr * 256 + bb * 16 + j0 + 1];
        float az1 = scr[(2 + Tr) * 256 + bb * 16 + j0], az2 = scr[(2 + Tr) * 256 + bb * 16 + j0 + 1];
        float an1 = scr[(4 + Tr) * 256 + bb * 16 + j0], an2 = scr[(4 + Tr) * 256 + bb * 16 + j0 + 1];
        float r1 = sigm(ar1 + gir1 + bhr1);
        float z1 = sigm(az1 + giz1 + bhz1);
        float n1 = tanhfast(gin1 + r1 * (an1 + bhn1));
        float h1 = (1.f - z1) * n1 + z1 * hprev1; hprev1 = h1;
        float r2 = sigm(ar2 + gir2 + bhr2);
        float z2 = sigm(az2 + giz2 + bhz2);
        float n2 = tanhfast(gin2 + r2 * (an2 + bhn2));
        float h2 = (1.f - z2) * n2 + z2 * hprev2; hprev2 = h2;
        u32x2 hv = { pk2(h1, h2), (unsigned int)(t + 1) };
        unsigned long long* hdst = hq + (size_t)(t & (HQ_SLOTS - 1)) * 4096
                                      + (size_t)bb * 256 + w * 16 + dp;
        asm volatile("global_store_dwordx2 %0, %1, off sc0 sc1" :: "v"(hdst), "v"(hv) : "memory");
        gir1 = nir1; giz1 = niz1; gin1 = nin1;
        gir2 = nir2; giz2 = niz2; gin2 = nin2;
      } else {
        const int Tg = dp >> 3, j0 = (2 * dp) & 15;
        float g0 = scr[Tg * 256 + bb * 16 + j0] + bgc0,       g1 = scr[Tg * 256 + bb * 16 + j0 + 1] + bgc1;
        float x0 = scr[(2 + Tg) * 256 + bb * 16 + j0] + bxc0, x1 = scr[(2 + Tg) * 256 + bb * 16 + j0 + 1] + bxc1;
        float p0 = scr[(4 + Tg) * 256 + bb * 16 + j0] + bpc0, p1 = scr[(4 + Tg) * 256 + bb * 16 + j0 + 1] + bpc1;
        u32x4 rec = { pk2(g0, g1), pk2(x0, x1), pk2(p0, p1), (unsigned int)(t + 1) };
        u32x4* rdst = recS + ((size_t)t * 16 + bb) * 128 + w * 16 + dp;
        asm volatile("global_store_dwordx4 %0, %1, off sc0 sc1" :: "v"(rdst), "v"(rec) : "memory");
      }
    }
  } else {
    // ---- consumers: 32 blocks x 4 independent waves = 128 M-slices ----
    const int id = wid - 24;            // 0..31
    const int b = id >> 1, sg = id & 1;
    const int sl = sg * 4 + v;          // slice 0..7
    float* Msh = (float*)(smem + v * 32768);  // [256][32] f32
    const int colg = lane & 7, dgs = lane >> 3;
    for (int i = lane * 4; i < 8192; i += 256) *(float4*)&Msh[i] = float4{0.f, 0.f, 0.f, 0.f};
    // no cross-wave sharing: waves fully independent (no syncthreads needed)
    #pragma unroll 1
    for (int t = 0; t < L_SEQ; ++t) {
      const u32x4* rp = recS + ((size_t)t * 16 + b) * 128 + 2 * lane;
      const unsigned int tagv = (unsigned int)(t + 1);
      u32x4 r0, r1;
      int spins = 0;
      for (;;) {
        asm volatile(
          "global_load_dwordx4 %0, %2, off sc0 sc1\n\t"
          "global_load_dwordx4 %1, %2, off offset:16 sc0 sc1\n\t"
          "s_waitcnt vmcnt(0)"
          : "=&v"(r0), "=&v"(r1) : "v"(rp) : "memory");
        if (__all((r0.w == tagv) && (r1.w == tagv))) break;
        if (++spins > 2000000) break;
      }
      const int lx = sl * 8 + colg;
      unsigned int xa = (unsigned int)__shfl((int)r0.y, lx);
      unsigned int xb = (unsigned int)__shfl((int)r1.y, lx);
      unsigned int pa = (unsigned int)__shfl((int)r0.z, lx);
      unsigned int pb = (unsigned int)__shfl((int)r1.z, lx);
      float xv0 = bf2f(xa), xv1 = bf2f(xa >> 16), xv2 = bf2f(xb), xv3 = bf2f(xb >> 16);
      float r0a = 0, r1a = 0, r2a = 0, r3a = 0;
      #pragma unroll
      for (int ic = 0; ic < 8; ++ic) {
        const int ls = dgs * 8 + ic;
        unsigned int ga = (unsigned int)__shfl((int)r0.x, ls);
        unsigned int gb = (unsigned int)__shfl((int)r1.x, ls);
        float gj[4] = { bf2f(ga), bf2f(ga >> 16), bf2f(gb), bf2f(gb >> 16) };
        int dg = dgs * 32 + ic * 4;
        #pragma unroll
        for (int j = 0; j < 4; ++j) {
          float4* mp = (float4*)&Msh[(dg + j) * 32 + colg * 4];
          float4 m = *mp;
          r0a += gj[j] * m.x; r1a += gj[j] * m.y; r2a += gj[j] * m.z; r3a += gj[j] * m.w;
          m.x += gj[j] * xv0; m.y += gj[j] * xv1; m.z += gj[j] * xv2; m.w += gj[j] * xv3;
          *mp = m;
        }
      }
      #pragma unroll
      for (int off = 8; off < 64; off <<= 1) {
        r0a += __shfl_xor(r0a, off); r1a += __shfl_xor(r1a, off);
        r2a += __shfl_xor(r2a, off); r3a += __shfl_xor(r3a, off);
      }
      if (dgs == 0) {
        float y0 = 0.5f * bf2f(pa) + 0.5f * r0a;
        float y1 = 0.5f * bf2f(pa >> 16) + 0.5f * r1a;
        float y2 = 0.5f * bf2f(pb) + 0.5f * r2a;
        float y3 = 0.5f * bf2f(pb >> 16) + 0.5f * r3a;
        uint2 ou = { pk2(y0, y1), pk2(y2, y3) };
        *(uint2*)(xhat + ((size_t)t * 16 + b) * 256 + sl * 32 + colg * 4) = ou;
      }
    }
  }
}

// ---------------- K3: LayerNorm in place over x_hat rows ----------------
__global__ __launch_bounds__(256) void k_ln(
    unsigned short* xh, const float* __restrict__ g, const float* __restrict__ bta)
{
  int row = blockIdx.x * 4 + (threadIdx.x >> 6);
  int lane = threadIdx.x & 63;
  size_t base = (size_t)row * 256 + lane * 4;
  uint2 raw = *(const uint2*)(xh + base);
  float v0 = bf2f(raw.x), v1 = bf2f(raw.x >> 16), v2 = bf2f(raw.y), v3 = bf2f(raw.y >> 16);
  float s1 = v0 + v1 + v2 + v3;
  float s2 = v0 * v0 + v1 * v1 + v2 * v2 + v3 * v3;
  #pragma unroll
  for (int off = 1; off < 64; off <<= 1) { s1 += __shfl_xor(s1, off); s2 += __shfl_xor(s2, off); }
  float mu = s1 * (1.f / 256.f);
  float var = s2 * (1.f / 256.f) - mu * mu;
  float rs = rsqrtf(var + 1e-5f);
  int c = lane * 4;
  float y0 = (v0 - mu) * rs * g[c] + bta[c];
  float y1 = (v1 - mu) * rs * g[c + 1] + bta[c + 1];
  float y2 = (v2 - mu) * rs * g[c + 2] + bta[c + 2];
  float y3 = (v3 - mu) * rs * g[c + 3] + bta[c + 3];
  uint2 ou = { pk2(y0, y1), pk2(y2, y3) };
  *(uint2*)(xh + base) = ou;
}

// ---------------- K4: logits = LN(x_hat) @ Wo^T + bo -> out (B,L,V) f32 ----------------
__global__ __launch_bounds__(256) void k_logits(
    const unsigned short* __restrict__ ln, const float* __restrict__ Wo,
    const float* __restrict__ bo, float* __restrict__ out)
{
  __shared__ unsigned short As[64 * KPAD];
  __shared__ unsigned short Bs[64 * KPAD];
  const int tid = threadIdx.x, lane = tid & 63, wv = tid >> 6;
  const int m0 = blockIdx.y * 64, n0 = blockIdx.x * 64;
  const int sr = tid >> 2, skc = (tid & 3) * 8;
  const unsigned short* asrc = ln + (size_t)(m0 + sr) * 256 + skc;
  const int brow = n0 + sr;
  const bool bok = brow < V_SZ;
  const float* bsrc = Wo + (size_t)(bok ? brow : 0) * 256 + skc;

  f32x4 acc[4];
  #pragma unroll
  for (int i = 0; i < 4; ++i) acc[i] = 0.f;

  for (int ks = 0; ks < 8; ++ks) {
    __syncthreads();
    *(uint4*)&As[sr * KPAD + skc] = *(const uint4*)(asrc + ks * 32);
    uint4 ub = {0u, 0u, 0u, 0u};
    if (bok) {
      float4 q0 = *(const float4*)(bsrc + ks * 32);
      float4 q1 = *(const float4*)(bsrc + ks * 32 + 4);
      ub.x = pk2(q0.x, q0.y); ub.y = pk2(q0.z, q0.w);
      ub.z = pk2(q1.x, q1.y); ub.w = pk2(q1.z, q1.w);
    }
    *(uint4*)&Bs[sr * KPAD + skc] = ub;
    __syncthreads();
    bf16x8 af = *(const bf16x8*)&As[(wv * 16 + (lane & 15)) * KPAD + (lane >> 4) * 8];
    #pragma unroll
    for (int ns = 0; ns < 4; ++ns) {
      bf16x8 bfv = *(const bf16x8*)&Bs[(ns * 16 + (lane & 15)) * KPAD + (lane >> 4) * 8];
      acc[ns] = __builtin_amdgcn_mfma_f32_16x16x32_bf16(af, bfv, acc[ns], 0, 0, 0);
    }
  }
  const int mrow = m0 + wv * 16 + 4 * (lane >> 4);
  const int ncol = n0 + (lane & 15);
  #pragma unroll
  for (int ns = 0; ns < 4; ++ns) {
    int col = ncol + ns * 16;
    if (col < V_SZ) {
      float bv = bo[col];
      #pragma unroll
      for (int rr = 0; rr < 4; ++rr) {
        int row = mrow + rr;
        out[(size_t)(row & 15) * ((size_t)L_SEQ * V_SZ) + (size_t)(row >> 4) * V_SZ + col] =
            acc[ns][rr] + bv;
      }
    }
  }
}

extern "C" void kernel_launch(void* const* d_in, const int* in_sizes, int n_in,
                              void* d_out, int out_size, void* d_ws, size_t ws_size,
                              hipStream_t stream)
{
  const int*   tokens = (const int*)d_in[0];
  const float* emb    = (const float*)d_in[1];
  const float* Wih    = (const float*)d_in[2];
  const float* Whh    = (const float*)d_in[3];
  const float* bih    = (const float*)d_in[4];
  const float* bhh    = (const float*)d_in[5];
  const float* Wg     = (const float*)d_in[6];
  const float* bg     = (const float*)d_in[7];
  const float* Wx     = (const float*)d_in[8];
  const float* bx     = (const float*)d_in[9];
  const float* Wp     = (const float*)d_in[10];
  const float* bp     = (const float*)d_in[11];
  const float* lng    = (const float*)d_in[12];
  const float* lnb    = (const float*)d_in[13];
  const float* Wo     = (const float*)d_in[14];
  const float* bo     = (const float*)d_in[15];
  float* out = (float*)d_out;

  char* ws = (char*)d_ws;
  size_t off = 0;
  auto take = [&](size_t bytes) -> char* {
    char* p = ws + off;
    off += (bytes + 255) & ~(size_t)255;
    return p;
  };
  unsigned short* giT    = (unsigned short*)take((size_t)1024 * 1536 * 16 * 2);  // 50.33 MB
  u32x4* recS            = (u32x4*)take((size_t)1024 * 16 * 128 * 16);           // 33.55 MB
  unsigned short* xhat   = (unsigned short*)take((size_t)1024 * 16 * 256 * 2);   // 8.39 MB
  unsigned long long* hq = (unsigned long long*)take((size_t)HQ_SLOTS * 4096 * 8); // 256 KB
  if (off > ws_size) return;

  (void)hipMemsetAsync(recS, 0, (size_t)1024 * 16 * 128 * 16, stream);
  (void)hipMemsetAsync(hq, 0, (size_t)HQ_SLOTS * 4096 * 8, stream);

  k_gi<<<dim3(24, 256), 256, 0, stream>>>(tokens, emb, Wih, bih, giT);
  k_scan<<<56, 256, 0, stream>>>(giT, Whh, bhh, Wg, bg, Wx, bx, Wp, bp,
                                 recS, xhat, hq);
  k_ln<<<4096, 256, 0, stream>>>(xhat, lng, lnb);
  k_logits<<<dim3(157, 256), 256, 0, stream>>>(xhat, Wo, bo, out);
}